// Round 24
// baseline (715.440 us; speedup 1.0000x reference)
//
#include <hip/hip_runtime.h>

// ---------------------------------------------------------------------------
// VQ-VAE forward.  N=128.  MFMA (split-bf16 hi/lo, 3-term) for the four
// 3x3 64->64 convs, dec2 (up2x + 3x3 64->32), enc2 (4x4 s2 32->64), the
// VQ distance GEMM, and the three 1x1 channel GEMMs.  f32 VALU elsewhere.
//   x*y ~= xh*yh + xh*yl + xl*yh   (f32 MFMA accumulate)
// Activations staged in LDS as PACKED (hi | lo<<16) u32, pad 20 (proven).
// R22: dec2m interp writes vectorized (reg-accumulate + ds_write_b128).
// R23: dec3 s_up chunk-parity layout (conflicts 16.8M -> 10.1M).
// R24: dec3 min-waves 4 -> 5 (29184B x 5 = 145.9KB < 160KB; VGPR 52 << 102).
// ---------------------------------------------------------------------------

template<int ACT> __device__ __forceinline__ float actf(float x){
  if (ACT == 1) return x > 0.f ? x : 0.01f * x;   // leaky relu, slope .01
  if (ACT == 2) return fmaxf(x, 0.f);             // relu
  return x;
}

typedef __bf16 bf16x8 __attribute__((ext_vector_type(8)));
typedef float f32x16 __attribute__((ext_vector_type(16)));
typedef unsigned int u32x4v __attribute__((ext_vector_type(4)));

__device__ __forceinline__ unsigned f2bf(unsigned u){   // RTNE f32->bf16 bits
  return (u + 0x7fffu + ((u >> 16) & 1u)) >> 16;
}

// ---------------- weight prep: f32 [64co][64ci][3][3] -> hi/lo bf16 --------
__global__ __launch_bounds__(256) void k_wprep(
    const float* __restrict__ w, unsigned short* __restrict__ wh,
    unsigned short* __restrict__ wl) {
  int i = blockIdx.x * 256 + threadIdx.x;           // 36864 = 4g*9tap*2*32*16
  if (i >= 36864) return;
  int ci16 = i & 15, co = (i >> 4) & 31, cot = (i >> 9) & 1;
  int rest = i >> 10, tap = rest % 9, g = rest / 9;
  float v = w[(cot * 32 + co) * 576 + (g * 16 + ci16) * 9 + tap];
  unsigned hi = f2bf(__float_as_uint(v));
  float lf = v - __uint_as_float(hi << 16);
  unsigned lo = f2bf(__float_as_uint(lf));
  wh[i] = (unsigned short)hi;
  wl[i] = (unsigned short)lo;
}

// ---------------- weight prep for dec2: f32 [32co][64ci][3][3] -------------
__global__ __launch_bounds__(256) void k_wprep2(
    const float* __restrict__ w, unsigned short* __restrict__ wh,
    unsigned short* __restrict__ wl) {
  int i = blockIdx.x * 256 + threadIdx.x;           // 18432 = 4g*9tap*32*16
  if (i >= 18432) return;
  int ci16 = i & 15, co = (i >> 4) & 31;
  int rest = i >> 9, tap = rest % 9, g = rest / 9;
  float v = w[co * 576 + (g * 16 + ci16) * 9 + tap];
  unsigned hi = f2bf(__float_as_uint(v));
  float lf = v - __uint_as_float(hi << 16);
  unsigned lo = f2bf(__float_as_uint(lf));
  wh[i] = (unsigned short)hi;
  wl[i] = (unsigned short)lo;
}

// ---------------- weight prep for enc2: f32 [64co][32ci][4][4] -------------
__global__ __launch_bounds__(256) void k_wprep_e2(
    const float* __restrict__ w, unsigned short* __restrict__ wh,
    unsigned short* __restrict__ wl) {
  int i = blockIdx.x * 256 + threadIdx.x;           // 32768 = 2g*16tap*2*32*16
  if (i >= 32768) return;
  int ci16 = i & 15, co = (i >> 4) & 31, cot = (i >> 9) & 1;
  int rest = i >> 10, tap = rest & 15, g = rest >> 4;
  float v = w[(cot * 32 + co) * 512 + (g * 16 + ci16) * 16 + tap];
  unsigned hi = f2bf(__float_as_uint(v));
  float lf = v - __uint_as_float(hi << 16);
  unsigned lo = f2bf(__float_as_uint(lf));
  wh[i] = (unsigned short)hi;
  wl[i] = (unsigned short)lo;
}

// ---------------- codebook prep for VQ MFMA: fragment-ordered hi/lo --------
__global__ __launch_bounds__(256) void k_cbprep_m(
    const float* __restrict__ cb, unsigned short* __restrict__ ch,
    unsigned short* __restrict__ cl_) {
  int i = blockIdx.x * 256 + threadIdx.x;           // 32768 = 16ct*4s*32*16
  if (i >= 32768) return;
  int ci16 = i & 15, cc = (i >> 4) & 31, ct4s = i >> 9;
  int s = ct4s & 3, ct = ct4s >> 2;
  float v = cb[(ct * 32 + cc) * 64 + s * 16 + ci16];
  unsigned hi = f2bf(__float_as_uint(v));
  float lf = v - __uint_as_float(hi << 16);
  unsigned lo = f2bf(__float_as_uint(lf));
  ch[i] = (unsigned short)hi;
  cl_[i] = (unsigned short)lo;
}

// ---------------- weight prep for 1x1: f32 [64co][64ci] --------------------
__global__ __launch_bounds__(256) void k_wprep_1x1(
    const float* __restrict__ w, unsigned short* __restrict__ wh,
    unsigned short* __restrict__ wl) {
  int i = blockIdx.x * 256 + threadIdx.x;           // 4096 = 2ct*4s*32*16
  if (i >= 4096) return;
  int ci16 = i & 15, cc = (i >> 4) & 31, s = (i >> 9) & 3, ct = i >> 11;
  float v = w[(ct * 32 + cc) * 64 + s * 16 + ci16];
  unsigned hi = f2bf(__float_as_uint(v));
  float lf = v - __uint_as_float(hi << 16);
  unsigned lo = f2bf(__float_as_uint(lf));
  wh[i] = (unsigned short)hi;
  wl[i] = (unsigned short)lo;
}

// ---------------- codebook squared norms -----------------------------------
__global__ __launch_bounds__(256) void k_cbnorm(const float* __restrict__ cb,
                                                float* __restrict__ nrm) {
  int c = blockIdx.x * 256 + threadIdx.x;
  if (c < 512) {
    float s = 0.f;
    for (int k = 0; k < 64; ++k) { float v = cb[c * 64 + k]; s = fmaf(v, v, s); }
    nrm[c] = s;
  }
}

// ---------------- enc1: 1->32, 4x4 s2 p1, 128->64, lrelu (LDS-staged) ------
__global__ __launch_bounds__(256) void k_enc1m(
    const float* __restrict__ in, const float* __restrict__ w,
    const float* __restrict__ b, float* __restrict__ out) {
  int n = blockIdx.x >> 3, y0 = (blockIdx.x & 7) * 8;
  int t = threadIdx.x;
  __shared__ float s_in[18 * 2 * 66];   // [r][parity][col/2], cols -1..128
  __shared__ float s_w[512];
  __shared__ float s_b[32];
  const float* ip = in + n * 16384;
  for (int i = t; i < 18 * 130; i += 256) {
    int r = i / 130, c = i - r * 130;
    int iy = 2 * y0 - 1 + r, ix = c - 1;
    float v = 0.f;
    if ((unsigned)iy < 128u && (unsigned)ix < 128u) v = ip[iy * 128 + ix];
    s_in[(r * 2 + (c & 1)) * 66 + (c >> 1)] = v;
  }
  for (int i = t; i < 512; i += 256) s_w[i] = w[i];
  if (t < 32) s_b[t] = b[t];
  __syncthreads();
  int ox = t & 63, wv = t >> 6;
#pragma unroll
  for (int rr = 0; rr < 2; ++rr) {
    int oyl = wv * 2 + rr;
    float x[16];
#pragma unroll
    for (int ky = 0; ky < 4; ++ky) {
      int r = 2 * oyl + ky;
#pragma unroll
      for (int kx = 0; kx < 4; ++kx) {
        x[ky * 4 + kx] = s_in[(r * 2 + (kx & 1)) * 66 + ox + (kx >> 1)];
      }
    }
    int obase = (n * 32) * 4096 + (y0 + oyl) * 64 + ox;
    for (int co = 0; co < 32; ++co) {
      float acc = s_b[co];
      const float* wr = &s_w[co * 16];
#pragma unroll
      for (int k = 0; k < 16; ++k) acc = fmaf(x[k], wr[k], acc);
      out[obase + co * 4096] = actf<1>(acc);
    }
  }
}

// ---------------- 3x3 64->64 stride1 pad1 @32x32 via MFMA ------------------
template<int ACT, bool BIAS>
__global__ __launch_bounds__(256, 3) void k_conv3m(
    const float* __restrict__ in, const unsigned short* __restrict__ wh,
    const unsigned short* __restrict__ wl, const float* __restrict__ bias,
    float* __restrict__ out) {
  int n = blockIdx.x >> 2, y0 = (blockIdx.x & 3) * 8;
  int t = threadIdx.x;
  int lane = t & 63, wv = t >> 6;
  int cot = wv & 1, rgroup = wv >> 1;
  int cc = lane & 31, h = lane >> 5;

  __shared__ __align__(16) unsigned int s_x[6800];   // [10 r][34 c][pad 20 ci]

  const uint4* wh4 = reinterpret_cast<const uint4*>(wh);
  const uint4* wl4 = reinterpret_cast<const uint4*>(wl);

  f32x16 acc[4];
#pragma unroll
  for (int r = 0; r < 4; ++r)
#pragma unroll
    for (int j = 0; j < 16; ++j) acc[r][j] = 0.f;

  for (int g = 0; g < 4; ++g) {
    if (g) __syncthreads();
    for (int i = t; i < 5440; i += 256) {
      int c = i % 34; int rem = i / 34; int r = rem % 10; int ci = rem / 10;
      int row = y0 - 1 + r, col = c - 1;
      float v = 0.f;
      if ((unsigned)row < 32u && (unsigned)col < 32u)
        v = in[(n * 64 + g * 16 + ci) * 1024 + row * 32 + col];
      unsigned hi = f2bf(__float_as_uint(v));
      float lf = v - __uint_as_float(hi << 16);
      unsigned lo = f2bf(__float_as_uint(lf));
      s_x[(r * 34 + c) * 20 + ci] = hi | (lo << 16);
    }
    __syncthreads();

#pragma unroll
    for (int kx = 0; kx < 3; ++kx) {
      bf16x8 Ah[3], Al[3];
#pragma unroll
      for (int ky = 0; ky < 3; ++ky) {
        int wi = ((g * 9 + ky * 3 + kx) * 2 + cot) * 64 + cc * 2 + h;
        Ah[ky] = __builtin_bit_cast(bf16x8, wh4[wi]);
        Al[ky] = __builtin_bit_cast(bf16x8, wl4[wi]);
      }
#pragma unroll
      for (int ir6 = 0; ir6 < 6; ++ir6) {
        int ir = rgroup * 4 + ir6;
        const uint4* xp = reinterpret_cast<const uint4*>(
            &s_x[(ir * 34 + cc + kx) * 20 + (h << 3)]);
        uint4 qa = xp[0], qb = xp[1];
        u32x4v bh, bl;
        bh[0] = (qa.x & 0xffffu) | (qa.y << 16);
        bh[1] = (qa.z & 0xffffu) | (qa.w << 16);
        bh[2] = (qb.x & 0xffffu) | (qb.y << 16);
        bh[3] = (qb.z & 0xffffu) | (qb.w << 16);
        bl[0] = (qa.x >> 16) | (qa.y & 0xffff0000u);
        bl[1] = (qa.z >> 16) | (qa.w & 0xffff0000u);
        bl[2] = (qb.x >> 16) | (qb.y & 0xffff0000u);
        bl[3] = (qb.z >> 16) | (qb.w & 0xffff0000u);
        bf16x8 Bh = __builtin_bit_cast(bf16x8, bh);
        bf16x8 Bl = __builtin_bit_cast(bf16x8, bl);
#pragma unroll
        for (int ky = 0; ky < 3; ++ky) {
          int rr = ir6 - ky;
          if (rr < 0 || rr > 3) continue;
          acc[rr] = __builtin_amdgcn_mfma_f32_32x32x16_bf16(Ah[ky], Bh, acc[rr], 0, 0, 0);
          acc[rr] = __builtin_amdgcn_mfma_f32_32x32x16_bf16(Ah[ky], Bl, acc[rr], 0, 0, 0);
          acc[rr] = __builtin_amdgcn_mfma_f32_32x32x16_bf16(Al[ky], Bh, acc[rr], 0, 0, 0);
        }
      }
    }
  }

  float bvv[16];
#pragma unroll
  for (int reg = 0; reg < 16; ++reg) {
    int row = (reg & 3) + 8 * (reg >> 2) + 4 * h;
    bvv[reg] = BIAS ? bias[cot * 32 + row] : 0.f;
  }
#pragma unroll
  for (int rr = 0; rr < 4; ++rr) {
    int y = y0 + rgroup * 4 + rr;
#pragma unroll
    for (int reg = 0; reg < 16; ++reg) {
      int row = (reg & 3) + 8 * (reg >> 2) + 4 * h;
      int co = cot * 32 + row;
      float v = acc[rr][reg] + bvv[reg];
      out[(n * 64 + co) * 1024 + y * 32 + cc] = actf<ACT>(v);
    }
  }
}

// ---------------- enc2: 32->64, 4x4 s2 p1, 64->32 via MFMA -----------------
__global__ __launch_bounds__(256, 2) void k_enc2m(
    const float* __restrict__ in, const unsigned short* __restrict__ wh,
    const unsigned short* __restrict__ wl, const float* __restrict__ bias,
    float* __restrict__ out) {
  int n = blockIdx.x >> 3, y0 = (blockIdx.x & 7) * 4;
  int t = threadIdx.x;
  int lane = t & 63, wv = t >> 6;
  int cot = wv & 1, rg = wv >> 1;
  int cc = lane & 31, h = lane >> 5;

  __shared__ __align__(16) unsigned int s_x[13200];  // [10][2][33][20]

  const uint4* wh4 = reinterpret_cast<const uint4*>(wh);
  const uint4* wl4 = reinterpret_cast<const uint4*>(wl);

  f32x16 acc[2];
#pragma unroll
  for (int r = 0; r < 2; ++r)
#pragma unroll
    for (int j = 0; j < 16; ++j) acc[r][j] = 0.f;

  for (int g = 0; g < 2; ++g) {
    if (g) __syncthreads();
    for (int i = t; i < 10560; i += 256) {
      int ci = i / 660, rem = i - ci * 660;
      int r = rem / 66, c = rem - r * 66;
      int row = 2 * y0 - 1 + r, icol = c - 1;
      float v = 0.f;
      if ((unsigned)row < 64u && (unsigned)icol < 64u)
        v = in[((n * 32 + g * 16 + ci) * 64 + row) * 64 + icol];
      unsigned hi = f2bf(__float_as_uint(v));
      float lf = v - __uint_as_float(hi << 16);
      unsigned lo = f2bf(__float_as_uint(lf));
      int p = icol & 1;
      int idx = (icol + p) >> 1;
      s_x[((r * 2 + p) * 33 + idx) * 20 + ci] = hi | (lo << 16);
    }
    __syncthreads();

#pragma unroll
    for (int kx = 0; kx < 4; ++kx) {
      bf16x8 Ah[4], Al[4];
#pragma unroll
      for (int ky = 0; ky < 4; ++ky) {
        int wi = ((g * 16 + ky * 4 + kx) * 2 + cot) * 64 + cc * 2 + h;
        Ah[ky] = __builtin_bit_cast(bf16x8, wh4[wi]);
        Al[ky] = __builtin_bit_cast(bf16x8, wl4[wi]);
      }
      int p = (kx + 1) & 1;
      int idx = cc + (kx >> 1);
#pragma unroll
      for (int ir6 = 0; ir6 < 6; ++ir6) {
        int r = rg * 4 + ir6;
        const uint4* xp = reinterpret_cast<const uint4*>(
            &s_x[((r * 2 + p) * 33 + idx) * 20 + (h << 3)]);
        uint4 qa = xp[0], qb = xp[1];
        u32x4v bh, bl;
        bh[0] = (qa.x & 0xffffu) | (qa.y << 16);
        bh[1] = (qa.z & 0xffffu) | (qa.w << 16);
        bh[2] = (qb.x & 0xffffu) | (qb.y << 16);
        bh[3] = (qb.z & 0xffffu) | (qb.w << 16);
        bl[0] = (qa.x >> 16) | (qa.y & 0xffff0000u);
        bl[1] = (qa.z >> 16) | (qa.w & 0xffff0000u);
        bl[2] = (qb.x >> 16) | (qb.y & 0xffff0000u);
        bl[3] = (qb.z >> 16) | (qb.w & 0xffff0000u);
        bf16x8 Bh = __builtin_bit_cast(bf16x8, bh);
        bf16x8 Bl = __builtin_bit_cast(bf16x8, bl);
#pragma unroll
        for (int rr = 0; rr < 2; ++rr) {
          int ky = ir6 - 2 * rr;
          if (ky < 0 || ky > 3) continue;
          acc[rr] = __builtin_amdgcn_mfma_f32_32x32x16_bf16(Ah[ky], Bh, acc[rr], 0, 0, 0);
          acc[rr] = __builtin_amdgcn_mfma_f32_32x32x16_bf16(Ah[ky], Bl, acc[rr], 0, 0, 0);
          acc[rr] = __builtin_amdgcn_mfma_f32_32x32x16_bf16(Al[ky], Bh, acc[rr], 0, 0, 0);
        }
      }
    }
  }

#pragma unroll
  for (int rr = 0; rr < 2; ++rr) {
    int oy = y0 + rg * 2 + rr;
#pragma unroll
    for (int reg = 0; reg < 16; ++reg) {
      int corow = (reg & 3) + 8 * (reg >> 2) + 4 * h;
      int co = cot * 32 + corow;
      float v = acc[rr][reg] + bias[co];
      out[(n * 64 + co) * 1024 + oy * 32 + cc] = actf<1>(v);
    }
  }
}

// ---------------- 1x1 64->64 via MFMA (vq2m-machinery subset) --------------
template<int ACT, bool BIAS, bool ADD>
__global__ __launch_bounds__(256, 2) void k_1x1m(
    const float* __restrict__ in, const unsigned short* __restrict__ wh,
    const unsigned short* __restrict__ wl, const float* __restrict__ bias,
    const float* __restrict__ add, float* __restrict__ out) {
  int bid = blockIdx.x;                  // 2048 = 128 n x 16 s-tiles
  int n = bid >> 4, s0 = (bid & 15) << 6;
  int t = threadIdx.x;
  int lane = t & 63, wv = t >> 6;
  int cc = lane & 31, h = lane >> 5;
  int ct = wv & 1, pt = wv >> 1;

  __shared__ __align__(16) unsigned int s_pk[5120];   // [4 s][64 pos][pad 20]

  for (int i = t; i < 4096; i += 256) {
    int pos = i & 63, k = i >> 6;
    float v = in[(n * 64 + k) * 1024 + s0 + pos];
    unsigned hi = f2bf(__float_as_uint(v));
    float lf = v - __uint_as_float(hi << 16);
    unsigned lo = f2bf(__float_as_uint(lf));
    s_pk[(((k >> 4) * 64) + pos) * 20 + (k & 15)] = hi | (lo << 16);
  }
  __syncthreads();

  const uint4* ah4 = reinterpret_cast<const uint4*>(wh);
  const uint4* al4 = reinterpret_cast<const uint4*>(wl);

  f32x16 acc;
#pragma unroll
  for (int j = 0; j < 16; ++j) acc[j] = 0.f;

#pragma unroll
  for (int s = 0; s < 4; ++s) {
    const uint4* xp = reinterpret_cast<const uint4*>(
        &s_pk[((s * 64) + pt * 32 + cc) * 20 + (h << 3)]);
    uint4 qa = xp[0], qb = xp[1];
    u32x4v bh, bl;
    bh[0] = (qa.x & 0xffffu) | (qa.y << 16);
    bh[1] = (qa.z & 0xffffu) | (qa.w << 16);
    bh[2] = (qb.x & 0xffffu) | (qb.y << 16);
    bh[3] = (qb.z & 0xffffu) | (qb.w << 16);
    bl[0] = (qa.x >> 16) | (qa.y & 0xffff0000u);
    bl[1] = (qa.z >> 16) | (qa.w & 0xffff0000u);
    bl[2] = (qb.x >> 16) | (qb.y & 0xffff0000u);
    bl[3] = (qb.z >> 16) | (qb.w & 0xffff0000u);
    bf16x8 Bh = __builtin_bit_cast(bf16x8, bh);
    bf16x8 Bl = __builtin_bit_cast(bf16x8, bl);
    int wi = (ct * 4 + s) * 64 + cc * 2 + h;
    bf16x8 Ah = __builtin_bit_cast(bf16x8, ah4[wi]);
    bf16x8 Al = __builtin_bit_cast(bf16x8, al4[wi]);
    acc = __builtin_amdgcn_mfma_f32_32x32x16_bf16(Ah, Bh, acc, 0, 0, 0);
    acc = __builtin_amdgcn_mfma_f32_32x32x16_bf16(Ah, Bl, acc, 0, 0, 0);
    acc = __builtin_amdgcn_mfma_f32_32x32x16_bf16(Al, Bh, acc, 0, 0, 0);
  }

  int pos = pt * 32 + cc;
#pragma unroll
  for (int reg = 0; reg < 16; ++reg) {
    int row = (reg & 3) + 8 * (reg >> 2) + 4 * h;
    int co = ct * 32 + row;
    float v = acc[reg] + (BIAS ? bias[co] : 0.f);
    int gi = (n * 64 + co) * 1024 + s0 + pos;
    if (ADD) v += add[gi];
    out[gi] = actf<ACT>(v);
  }
}

// ---------------- VQ via MFMA: dist GEMM + argmin + q + loss ---------------
__global__ __launch_bounds__(256, 2) void k_vq2m(
    const float* __restrict__ lat, const unsigned short* __restrict__ cbh,
    const unsigned short* __restrict__ cbl, const float* __restrict__ cb,
    const float* __restrict__ nrm, float* __restrict__ q,
    double* __restrict__ part) {
  int bid = blockIdx.x;                  // 2048 = 128 n x 16 s-tiles
  int n = bid >> 4, s0 = (bid & 15) << 6;
  int t = threadIdx.x;
  int lane = t & 63, wv = t >> 6;
  int cc = lane & 31, h = lane >> 5;

  __shared__ __align__(16) unsigned int s_pk[5120];   // [4 s][64 pos][pad 20]
  __shared__ float s_lat_f[4096];                     // [k][pos]
  __shared__ float s_nrm[512];
  __shared__ float s_rd[512];                         // [pos][8 slots]
  __shared__ int   s_ri[512];
  __shared__ int   s_sel[64];
  __shared__ double s_r[256];

  for (int i = t; i < 4096; i += 256) {
    int pos = i & 63, k = i >> 6;
    float v = lat[(n * 64 + k) * 1024 + s0 + pos];
    s_lat_f[k * 64 + pos] = v;
    unsigned hi = f2bf(__float_as_uint(v));
    float lf = v - __uint_as_float(hi << 16);
    unsigned lo = f2bf(__float_as_uint(lf));
    s_pk[(((k >> 4) * 64) + pos) * 20 + (k & 15)] = hi | (lo << 16);
  }
  for (int i = t; i < 512; i += 256) s_nrm[i] = nrm[i];
  __syncthreads();

  const uint4* ah4 = reinterpret_cast<const uint4*>(cbh);
  const uint4* al4 = reinterpret_cast<const uint4*>(cbl);

  float best[2] = {3.4e38f, 3.4e38f};
  int bidx[2] = {0, 0};

#pragma unroll
  for (int ip = 0; ip < 2; ++ip) {
    f32x16 acc[2][2];
#pragma unroll
    for (int a = 0; a < 2; ++a)
#pragma unroll
      for (int b = 0; b < 2; ++b)
#pragma unroll
        for (int j = 0; j < 16; ++j) acc[a][b][j] = 0.f;

#pragma unroll
    for (int s = 0; s < 4; ++s) {
      bf16x8 Bh[2], Bl[2];
#pragma unroll
      for (int pt = 0; pt < 2; ++pt) {
        const uint4* xp = reinterpret_cast<const uint4*>(
            &s_pk[((s * 64) + pt * 32 + cc) * 20 + (h << 3)]);
        uint4 qa = xp[0], qb = xp[1];
        u32x4v bh, bl;
        bh[0] = (qa.x & 0xffffu) | (qa.y << 16);
        bh[1] = (qa.z & 0xffffu) | (qa.w << 16);
        bh[2] = (qb.x & 0xffffu) | (qb.y << 16);
        bh[3] = (qb.z & 0xffffu) | (qb.w << 16);
        bl[0] = (qa.x >> 16) | (qa.y & 0xffff0000u);
        bl[1] = (qa.z >> 16) | (qa.w & 0xffff0000u);
        bl[2] = (qb.z >> 16) | (qb.w & 0xffff0000u);
        bl[2] = (qb.x >> 16) | (qb.y & 0xffff0000u);
        bl[3] = (qb.z >> 16) | (qb.w & 0xffff0000u);
        Bh[pt] = __builtin_bit_cast(bf16x8, bh);
        Bl[pt] = __builtin_bit_cast(bf16x8, bl);
      }
#pragma unroll
      for (int it2 = 0; it2 < 2; ++it2) {
        int ct = wv * 4 + ip * 2 + it2;
        int wi = (ct * 4 + s) * 64 + cc * 2 + h;
        bf16x8 Ah = __builtin_bit_cast(bf16x8, ah4[wi]);
        bf16x8 Al = __builtin_bit_cast(bf16x8, al4[wi]);
#pragma unroll
        for (int pt = 0; pt < 2; ++pt) {
          acc[it2][pt] = __builtin_amdgcn_mfma_f32_32x32x16_bf16(Ah, Bh[pt], acc[it2][pt], 0, 0, 0);
          acc[it2][pt] = __builtin_amdgcn_mfma_f32_32x32x16_bf16(Ah, Bl[pt], acc[it2][pt], 0, 0, 0);
          acc[it2][pt] = __builtin_amdgcn_mfma_f32_32x32x16_bf16(Al, Bh[pt], acc[it2][pt], 0, 0, 0);
        }
      }
    }

#pragma unroll
    for (int it2 = 0; it2 < 2; ++it2) {
      int ct = wv * 4 + ip * 2 + it2;
#pragma unroll
      for (int pt = 0; pt < 2; ++pt) {
#pragma unroll
        for (int reg = 0; reg < 16; ++reg) {
          int code = ct * 32 + (reg & 3) + 8 * (reg >> 2) + 4 * h;
          float d = fmaf(-2.f, acc[it2][pt][reg], s_nrm[code]);
          if (d < best[pt] || (d == best[pt] && code < bidx[pt])) {
            best[pt] = d; bidx[pt] = code;
          }
        }
      }
    }
  }

#pragma unroll
  for (int pt = 0; pt < 2; ++pt) {
    int pos = pt * 32 + cc;
    s_rd[pos * 8 + wv * 2 + h] = best[pt];
    s_ri[pos * 8 + wv * 2 + h] = bidx[pt];
  }
  __syncthreads();
  if (t < 64) {
    float bd = s_rd[t * 8]; int bi = s_ri[t * 8];
#pragma unroll
    for (int m = 1; m < 8; ++m) {
      float d = s_rd[t * 8 + m]; int ii = s_ri[t * 8 + m];
      if (d < bd || (d == bd && ii < bi)) { bd = d; bi = ii; }
    }
    s_sel[t] = bi;
  }
  __syncthreads();

  int pos = t & 63, dg = t >> 6;
  int bsel = s_sel[pos];
  const float* cw = cb + bsel * 64 + dg * 16;
  float psum = 0.f;
#pragma unroll
  for (int kk = 0; kk < 16; ++kk) {
    int k = dg * 16 + kk;
    float cv = cw[kk];
    float l = s_lat_f[k * 64 + pos];
    float df = cv - l;
    psum = fmaf(df, df, psum);
    q[(n * 64 + k) * 1024 + s0 + pos] = cv;
  }
  s_r[t] = (double)psum;
  __syncthreads();
  for (int str = 128; str > 0; str >>= 1) {
    if (t < str) s_r[t] += s_r[t + str];
    __syncthreads();
  }
  if (t == 0) part[bid] = s_r[0];
}

// ---------------- dec2: up2x(ac) + 3x3 64->32 + lrelu, via MFMA ------------
__global__ __launch_bounds__(256, 3) void k_dec2m(
    const float* __restrict__ in, const unsigned short* __restrict__ wh,
    const unsigned short* __restrict__ wl, const float* __restrict__ bias,
    float* __restrict__ out) {
  int n = blockIdx.x >> 4, y0 = (blockIdx.x & 15) * 4;
  int t = threadIdx.x;
  int lane = t & 63, wv = t >> 6;
  int xh = wv & 1, rg = wv >> 1;
  int cc = lane & 31, h = lane >> 5;

  __shared__ __align__(16) unsigned int s_x[6 * 66 * 20];   // packed up-tile
  __shared__ float s_src[16 * 165];                         // [ci][5r][33]
  __shared__ float2 s_wmy[6];
  __shared__ int2   s_ryp[6];
  __shared__ float2 s_wmx[66];
  __shared__ int2   s_rxp[66];

  const float sc = 31.0f / 63.0f;
  int r0 = (y0 == 0) ? 0 : (int)floorf((float)(y0 - 1) * sc);

  if (t < 6) {
    int uy = y0 - 1 + t;
    int uyc = min(max(uy, 0), 63);
    float sy = (float)uyc * sc;
    int iy0 = (int)floorf(sy);
    s_wmy[t] = make_float2(sy - (float)iy0, ((unsigned)uy < 64u) ? 1.f : 0.f);
    s_ryp[t] = make_int2(iy0 - r0, min(iy0 + 1, 31) - r0);
  }
  int xc = t - 64;
  if (xc >= 0 && xc < 66) {
    int ux = xc - 1;
    int uxc = min(max(ux, 0), 63);
    float sx = (float)uxc * sc;
    int ix0 = (int)floorf(sx);
    s_wmx[xc] = make_float2(sx - (float)ix0, ((unsigned)ux < 64u) ? 1.f : 0.f);
    s_rxp[xc] = make_int2(ix0, min(ix0 + 1, 31));
  }

  // stage g=0 src: 16 ci x 5 rows x 32 cols
  for (int i = t; i < 2560; i += 256) {
    int ci = i / 160, rem = i - ci * 160;
    int rr = rem >> 5, c = rem & 31;
    int row = r0 + rr;
    s_src[ci * 165 + rr * 33 + c] =
        (row < 32) ? in[(n * 64 + ci) * 1024 + row * 32 + c] : 0.f;
  }
  __syncthreads();

  // slot setup: slot 0 (pos = t) always valid; slot 1 (pos = t+256) for t<140
  int so00[2], so01[2], so10[2], so11[2], spos[2];
  float swy[2], swx[2], smm[2];
  bool sval1;
  {
    int p = t;
    int u = p / 66, c = p - u * 66;
    float2 wmy = s_wmy[u]; int2 ry = s_ryp[u];
    float2 wmx = s_wmx[c]; int2 rx = s_rxp[c];
    swy[0] = wmy.x; swx[0] = wmx.x; smm[0] = wmy.y * wmx.y;
    so00[0] = ry.x * 33 + rx.x; so01[0] = ry.x * 33 + rx.y;
    so10[0] = ry.y * 33 + rx.x; so11[0] = ry.y * 33 + rx.y;
    spos[0] = p * 20;
  }
  {
    int pos1 = t + 256;
    sval1 = pos1 < 396;
    int p = sval1 ? pos1 : 0;
    int u = p / 66, c = p - u * 66;
    float2 wmy = s_wmy[u]; int2 ry = s_ryp[u];
    float2 wmx = s_wmx[c]; int2 rx = s_rxp[c];
    swy[1] = wmy.x; swx[1] = wmx.x; smm[1] = wmy.y * wmx.y;
    so00[1] = ry.x * 33 + rx.x; so01[1] = ry.x * 33 + rx.y;
    so10[1] = ry.y * 33 + rx.x; so11[1] = ry.y * 33 + rx.y;
    spos[1] = p * 20;
  }

  const uint4* wh4 = reinterpret_cast<const uint4*>(wh);
  const uint4* wl4 = reinterpret_cast<const uint4*>(wl);

  f32x16 acc[2];
#pragma unroll
  for (int r = 0; r < 2; ++r)
#pragma unroll
    for (int j = 0; j < 16; ++j) acc[r][j] = 0.f;

  for (int g = 0; g < 4; ++g) {
    // ---- interp + split-pack into registers (static indices) ----
    unsigned pk0[16], pk1[16];
#pragma unroll
    for (int ci = 0; ci < 16; ++ci) {
      const float* sp = s_src + ci * 165;
      {
        float a00 = sp[so00[0]], a01 = sp[so01[0]];
        float a10 = sp[so10[0]], a11 = sp[so11[0]];
        float h0 = fmaf(a10 - a00, swy[0], a00);
        float h1 = fmaf(a11 - a01, swy[0], a01);
        float v = smm[0] * fmaf(h1 - h0, swx[0], h0);
        __bf16 hb = (__bf16)v;
        float hf = (float)hb;
        __bf16 lb = (__bf16)(v - hf);
        pk0[ci] = (unsigned)__builtin_bit_cast(unsigned short, hb)
                | ((unsigned)__builtin_bit_cast(unsigned short, lb) << 16);
      }
      {
        float a00 = sp[so00[1]], a01 = sp[so01[1]];
        float a10 = sp[so10[1]], a11 = sp[so11[1]];
        float h0 = fmaf(a10 - a00, swy[1], a00);
        float h1 = fmaf(a11 - a01, swy[1], a01);
        float v = smm[1] * fmaf(h1 - h0, swx[1], h0);
        __bf16 hb = (__bf16)v;
        float hf = (float)hb;
        __bf16 lb = (__bf16)(v - hf);
        pk1[ci] = (unsigned)__builtin_bit_cast(unsigned short, hb)
                | ((unsigned)__builtin_bit_cast(unsigned short, lb) << 16);
      }
    }
    // ---- vectorized LDS writes: 4 (+4) x ds_write_b128 ----
#pragma unroll
    for (int qd = 0; qd < 4; ++qd) {
      *reinterpret_cast<uint4*>(&s_x[spos[0] + qd * 4]) =
          make_uint4(pk0[qd * 4], pk0[qd * 4 + 1], pk0[qd * 4 + 2], pk0[qd * 4 + 3]);
    }
    if (sval1) {
#pragma unroll
      for (int qd = 0; qd < 4; ++qd) {
        *reinterpret_cast<uint4*>(&s_x[spos[1] + qd * 4]) =
            make_uint4(pk1[qd * 4], pk1[qd * 4 + 1], pk1[qd * 4 + 2], pk1[qd * 4 + 3]);
      }
    }
    __syncthreads();

    // ---- stage next src group (overlaps MFMA) ----
    if (g < 3) {
      int ci0 = (g + 1) * 16;
      for (int i = t; i < 2560; i += 256) {
        int ci = i / 160, rem = i - ci * 160;
        int rr = rem >> 5, c = rem & 31;
        int row = r0 + rr;
        s_src[ci * 165 + rr * 33 + c] =
            (row < 32) ? in[(n * 64 + ci0 + ci) * 1024 + row * 32 + c] : 0.f;
      }
    }

    // ---- MFMA ----
#pragma unroll
    for (int kx = 0; kx < 3; ++kx) {
      bf16x8 Ah[3], Al[3];
#pragma unroll
      for (int ky = 0; ky < 3; ++ky) {
        int wi = (g * 9 + ky * 3 + kx) * 64 + cc * 2 + h;
        Ah[ky] = __builtin_bit_cast(bf16x8, wh4[wi]);
        Al[ky] = __builtin_bit_cast(bf16x8, wl4[wi]);
      }
#pragma unroll
      for (int u6 = 0; u6 < 4; ++u6) {
        int u = rg * 2 + u6;
        const uint4* xp = reinterpret_cast<const uint4*>(
            &s_x[(u * 66 + xh * 32 + cc + kx) * 20 + (h << 3)]);
        uint4 qa = xp[0], qb = xp[1];
        u32x4v bh, bl;
        bh[0] = (qa.x & 0xffffu) | (qa.y << 16);
        bh[1] = (qa.z & 0xffffu) | (qa.w << 16);
        bh[2] = (qb.x & 0xffffu) | (qb.y << 16);
        bh[3] = (qb.z & 0xffffu) | (qb.w << 16);
        bl[0] = (qa.x >> 16) | (qa.y & 0xffff0000u);
        bl[1] = (qa.z >> 16) | (qa.w & 0xffff0000u);
        bl[2] = (qb.x >> 16) | (qb.y & 0xffff0000u);
        bl[3] = (qb.z >> 16) | (qb.w & 0xffff0000u);
        bf16x8 Bh = __builtin_bit_cast(bf16x8, bh);
        bf16x8 Bl = __builtin_bit_cast(bf16x8, bl);
#pragma unroll
        for (int ky = 0; ky < 3; ++ky) {
          int rr = u6 - ky;
          if (rr < 0 || rr > 1) continue;
          acc[rr] = __builtin_amdgcn_mfma_f32_32x32x16_bf16(Ah[ky], Bh, acc[rr], 0, 0, 0);
          acc[rr] = __builtin_amdgcn_mfma_f32_32x32x16_bf16(Ah[ky], Bl, acc[rr], 0, 0, 0);
          acc[rr] = __builtin_amdgcn_mfma_f32_32x32x16_bf16(Al[ky], Bh, acc[rr], 0, 0, 0);
        }
      }
    }
    __syncthreads();
  }

  float bvv[16];
#pragma unroll
  for (int reg = 0; reg < 16; ++reg) {
    int co = (reg & 3) + 8 * (reg >> 2) + 4 * h;
    bvv[reg] = bias[co];
  }
#pragma unroll
  for (int rr = 0; rr < 2; ++rr) {
    int y = y0 + rg * 2 + rr;
#pragma unroll
    for (int reg = 0; reg < 16; ++reg) {
      int co = (reg & 3) + 8 * (reg >> 2) + 4 * h;
      float v = acc[rr][reg] + bvv[reg];
      out[(n * 32 + co) * 4096 + y * 64 + xh * 32 + cc] = actf<1>(v);
    }
  }
}

// ---------------- loss finalize --------------------------------------------
__global__ __launch_bounds__(256) void k_loss(const double* __restrict__ part,
                                              float* __restrict__ out) {
  __shared__ double s[256];
  int t = threadIdx.x;
  double acc = 0.0;
  for (int i = t; i < 2048; i += 256) acc += part[i];
  s[t] = acc;
  __syncthreads();
  for (int str = 128; str > 0; str >>= 1) {
    if (t < str) s[t] += s[t + str];
    __syncthreads();
  }
  if (t == 0) {
    double mean = s[0] / 8388608.0;
    out[2097152] = (float)mean;
    out[2097153] = (float)(0.25 * mean);
  }
}

// ---------------- dec3: up2x(ac) + 3x3 32->1 + relu ------------------------
// FULL-WIDTH tiles: block = (n, 16-row strip), all 128 cols.
// R23 chunk-parity layout; R24 min-waves 5 (LDS 29184*5 = 145.9KB fits).
__global__ __launch_bounds__(256, 5) void k_dec3(
    const float* __restrict__ in, const float* __restrict__ w,
    const float* __restrict__ bias, float* __restrict__ out) {
  int bid = blockIdx.x;                  // 1024 = 128n * 8yT
  int n = bid >> 3, yT = bid & 7;
  int y0 = yT * 16;
  int t = threadIdx.x;
  int ty = t >> 4, xq = t & 15;          // 16 rows x 16 colgroups of 8

  __shared__ __align__(16) float s_up[2 * 18 * 136];  // [ci][18 u][34 chunks]
  __shared__ float s_src[2 * 11 * 66];   // [ci][11 r][64 c pad 66]
  __shared__ float s_w[288];
  __shared__ float2 s_wmy[18];
  __shared__ int2   s_ryp[18];
  __shared__ float2 s_wmx[130];
  __shared__ int2   s_rxp[130];

  const float sc = 63.0f / 127.0f;
  int r0 = (y0 == 0) ? 0 : (int)floorf((float)(y0 - 1) * sc);

  if (t < 18) {
    int uy = y0 - 1 + t;
    int uyc = min(max(uy, 0), 127);
    float sy = (float)uyc * sc;
    int iy0 = (int)floorf(sy);
    s_wmy[t] = make_float2(sy - (float)iy0, ((unsigned)uy < 128u) ? 1.f : 0.f);
    s_ryp[t] = make_int2(iy0 - r0, min(iy0 + 1, 63) - r0);
  }
  if (t < 130) {
    int ux = t - 1;
    int uxc = min(max(ux, 0), 127);
    float sx = (float)uxc * sc;
    int ix0 = (int)floorf(sx);
    s_wmx[t] = make_float2(sx - (float)ix0, ((unsigned)ux < 128u) ? 1.f : 0.f);
    s_rxp[t] = make_int2(ix0, min(ix0 + 1, 63));
  }
  for (int i = t; i < 288; i += 256) s_w[i] = w[i];

  float acc[8];
#pragma unroll
  for (int xx = 0; xx < 8; ++xx) acc[xx] = 0.f;

  // prologue stage g=0 (2 ci): aligned full-width rows
  for (int i = t; i < 2 * 11 * 64; i += 256) {
    int ci = i / 704, rem = i - ci * 704;
    int rr = rem >> 6, c = rem & 63;
    int row = r0 + rr;
    s_src[(ci * 11 + rr) * 66 + c] =
        (row < 64) ? in[((n * 32 + ci) * 64 + row) * 64 + c] : 0.f;
  }
  __syncthreads();

  for (int g = 0; g < 16; ++g) {
#pragma unroll
    for (int ci = 0; ci < 2; ++ci) {
      const float* sp = s_src + ci * 726;
      float* up = s_up + ci * 2448;      // 18 * 136
      for (int i = t; i < 2304; i += 256) {
        int u = i >> 7, c = i & 127;
        float2 wmy = s_wmy[u]; int2 ry = s_ryp[u];
        float2 wmx = s_wmx[c]; int2 rx = s_rxp[c];
        const float* r0p = sp + ry.x * 66;
        const float* r1p = sp + ry.y * 66;
        float a00 = r0p[rx.x], a01 = r0p[rx.y];
        float a10 = r1p[rx.x], a11 = r1p[rx.y];
        float h0 = fmaf(a10 - a00, wmy.x, a00);
        float h1 = fmaf(a11 - a01, wmy.x, a01);
        // chunk-parity position: k = c>>2; even -> k/2, odd -> 17 + k/2
        int cp = ((c & 4) ? (68 + ((c >> 3) << 2)) : ((c >> 3) << 2)) + (c & 3);
        up[u * 136 + cp] = (wmy.y * wmx.y) * fmaf(h1 - h0, wmx.x, h0);
      }
      if (t < 36) {
        int u = t >> 1, c = 128 + (t & 1);
        float2 wmy = s_wmy[u]; int2 ry = s_ryp[u];
        float2 wmx = s_wmx[c]; int2 rx = s_rxp[c];
        const float* r0p = sp + ry.x * 66;
        const float* r1p = sp + ry.y * 66;
        float a00 = r0p[rx.x], a01 = r0p[rx.y];
        float a10 = r1p[rx.x], a11 = r1p[rx.y];
        float h0 = fmaf(a10 - a00, wmy.x, a00);
        float h1 = fmaf(a11 - a01, wmy.x, a01);
        int cp = ((c & 4) ? (68 + ((c >> 3) << 2)) : ((c >> 3) << 2)) + (c & 3);
        up[u * 136 + cp] = (wmy.y * wmx.y) * fmaf(h1 - h0, wmx.x, h0);
      }
    }
    __syncthreads();

    if (g < 15) {
      int ci0 = (g + 1) * 2;
      for (int i = t; i < 2 * 11 * 64; i += 256) {
        int ci = i / 704, rem = i - ci * 704;
        int rr = rem >> 6, c = rem & 63;
        int row = r0 + rr;
        s_src[(ci * 11 + rr) * 66 + c] =
            (row < 64) ? in[((n * 32 + ci0 + ci) * 64 + row) * 64 + c] : 0.f;
      }
    }

    int ci0 = g * 2;
#pragma unroll
    for (int ci = 0; ci < 2; ++ci) {
#pragma unroll
      for (int ky = 0; ky < 3; ++ky) {
        int rbase = (ci * 18 + ty + ky) * 136;
        // chunks 2xq, 2xq+1, 2xq+2 -> float positions 4xq, 68+4xq, 4xq+4
        float4 q0 = *reinterpret_cast<const float4*>(&s_up[rbase + xq * 4]);
        float4 q1 = *reinterpret_cast<const float4*>(&s_up[rbase + 68 + xq * 4]);
        float4 q2 = *reinterpret_cast<const float4*>(&s_up[rbase + xq * 4 + 4]);
        float rv[12] = {q0.x, q0.y, q0.z, q0.w, q1.x, q1.y, q1.z, q1.w,
                        q2.x, q2.y, q2.z, q2.w};
#pragma unroll
        for (int kx = 0; kx < 3; ++kx) {
          float wv = s_w[(ci0 + ci) * 9 + ky * 3 + kx];
#pragma unroll
          for (int xx = 0; xx < 8; ++xx)
            acc[xx] = fmaf(rv[xx + kx], wv, acc[xx]);
        }
      }
    }
    __syncthreads();
  }
  float bv = bias[0];
  int base = n * 16384 + (y0 + ty) * 128 + xq * 8;
  float o[8];
#pragma unroll
  for (int xx = 0; xx < 8; ++xx) o[xx] = actf<2>(acc[xx] + bv);
  *reinterpret_cast<float4*>(&out[base]) = make_float4(o[0], o[1], o[2], o[3]);
  *reinterpret_cast<float4*>(&out[base + 4]) = make_float4(o[4], o[5], o[6], o[7]);
}

// ---------------------------------------------------------------------------
extern "C" void kernel_launch(void* const* d_in, const int* in_sizes, int n_in,
                              void* d_out, int out_size, void* d_ws, size_t ws_size,
                              hipStream_t stream) {
  (void)in_sizes; (void)n_in; (void)out_size; (void)ws_size;
  const float* x_in     = (const float*)d_in[0];
  const float* enc_w1   = (const float*)d_in[1];
  const float* enc_b1   = (const float*)d_in[2];
  const float* enc_w2   = (const float*)d_in[3];
  const float* enc_b2   = (const float*)d_in[4];
  const float* enc_w3   = (const float*)d_in[5];
  const float* enc_b3   = (const float*)d_in[6];
  const float* res_e_w1 = (const float*)d_in[7];
  const float* res_e_w2 = (const float*)d_in[8];
  const float* enc_w4   = (const float*)d_in[9];
  const float* enc_b4   = (const float*)d_in[10];
  const float* codebook = (const float*)d_in[11];
  const float* dec_w1   = (const float*)d_in[12];
  const float* dec_b1   = (const float*)d_in[13];
  const float* res_d_w1 = (const float*)d_in[14];
  const float* res_d_w2 = (const float*)d_in[15];
  const float* dec_w2   = (const float*)d_in[16];
  const float* dec_b2   = (const float*)d_in[17];
  const float* dec_w3   = (const float*)d_in[18];
  const float* dec_b3   = (const float*)d_in[19];
  float* out = (float*)d_out;

  char* ws = (char*)d_ws;
  float*  B0    = (float*)(ws);                         // 33.55 MB each
  float*  B1    = (float*)(ws + 33554432);
  float*  B2    = (float*)(ws + 67108864);
  float*  B3    = (float*)(ws + 100663296);
  float*  B4    = (float*)(ws + 134217728);             // enc1 out: 67.1 MB
  double* PART  = (double*)(ws + 201326592);
  float*  CNORM = (float*)(ws + 201326592 + 16384);
  unsigned short* CBH = (unsigned short*)(ws + 100663296);  // B3, pre-VQ only
  unsigned short* CBL = CBH + 32768;
  unsigned short* WH0 = (unsigned short*)(ws + 201359360);
  unsigned short* WL0 = WH0 + 36864;
  unsigned short* WH1 = (unsigned short*)(ws + 201359360 + 147456);
  unsigned short* WL1 = WH1 + 36864;
  unsigned short* WH2 = (unsigned short*)(ws + 201359360 + 294912);
  unsigned short* WL2 = WH2 + 36864;
  unsigned short* WH3 = (unsigned short*)(ws + 201359360 + 442368);
  unsigned short* WL3 = WH3 + 36864;
  unsigned short* WH4 = (unsigned short*)(ws + 201359360 + 589824);   // dec2
  unsigned short* WL4 = WH4 + 18432;
  unsigned short* WH5 = (unsigned short*)(ws + 201359360 + 663552);   // enc2
  unsigned short* WL5 = WH5 + 32768;
  unsigned short* WH6 = (unsigned short*)(ws + 202153984);            // res_e_w2
  unsigned short* WL6 = WH6 + 4096;
  unsigned short* WH7 = (unsigned short*)(ws + 202153984 + 16384);    // enc_w4
  unsigned short* WL7 = WH7 + 4096;
  unsigned short* WH8 = (unsigned short*)(ws + 202153984 + 32768);    // res_d_w2
  unsigned short* WL8 = WH8 + 4096;

  k_wprep<<<144, 256, 0, stream>>>(enc_w3,   WH0, WL0);
  k_wprep<<<144, 256, 0, stream>>>(res_e_w1, WH1, WL1);
  k_wprep<<<144, 256, 0, stream>>>(dec_w1,   WH2, WL2);
  k_wprep<<<144, 256, 0, stream>>>(res_d_w1, WH3, WL3);
  k_wprep2<<<72, 256, 0, stream>>>(dec_w2,   WH4, WL4);
  k_wprep_e2<<<128, 256, 0, stream>>>(enc_w2, WH5, WL5);
  k_wprep_1x1<<<16, 256, 0, stream>>>(res_e_w2, WH6, WL6);
  k_wprep_1x1<<<16, 256, 0, stream>>>(enc_w4,   WH7, WL7);
  k_wprep_1x1<<<16, 256, 0, stream>>>(res_d_w2, WH8, WL8);
  k_cbprep_m<<<128, 256, 0, stream>>>(codebook, CBH, CBL);
  k_cbnorm<<<2, 256, 0, stream>>>(codebook, CNORM);

  k_enc1m<<<1024, 256, 0, stream>>>(x_in, enc_w1, enc_b1, B4);
  k_enc2m<<<1024, 256, 0, stream>>>(B4, WH5, WL5, enc_b2, B0);
  k_conv3m<1, true ><<<512, 256, 0, stream>>>(B0, WH0, WL0, enc_b3, B1);
  k_conv3m<2, false><<<512, 256, 0, stream>>>(B1, WH1, WL1, nullptr, B2);
  k_1x1m<1, false, true ><<<2048, 256, 0, stream>>>(B2, WH6, WL6, nullptr, B1, B0);
  k_1x1m<1, true,  false><<<2048, 256, 0, stream>>>(B0, WH7, WL7, enc_b4, nullptr, B1);
  k_vq2m<<<2048, 256, 0, stream>>>(B1, CBH, CBL, codebook, CNORM, B2, PART);
  k_conv3m<1, true ><<<512, 256, 0, stream>>>(B2, WH2, WL2, dec_b1, B0);
  k_conv3m<2, false><<<512, 256, 0, stream>>>(B0, WH3, WL3, nullptr, B3);
  k_1x1m<1, false, true ><<<2048, 256, 0, stream>>>(B3, WH8, WL8, nullptr, B0, B1);
  k_dec2m<<<2048, 256, 0, stream>>>(B1, WH4, WL4, dec_b2, B4);
  k_dec3<<<1024, 256, 0, stream>>>(B4, dec_w3, dec_b3, out);
  k_loss<<<1, 256, 0, stream>>>(PART, out);
}

// Round 25
// 709.987 us; speedup vs baseline: 1.0077x; 1.0077x over previous
//
#include <hip/hip_runtime.h>

// ---------------------------------------------------------------------------
// VQ-VAE forward.  N=128.  MFMA (split-bf16 hi/lo, 3-term) for the four
// 3x3 64->64 convs, dec2 (up2x + 3x3 64->32), enc2 (4x4 s2 32->64), the
// VQ distance GEMM, and the three 1x1 channel GEMMs.  f32 VALU elsewhere.
//   x*y ~= xh*yh + xh*yl + xl*yh   (f32 MFMA accumulate)
// Activations staged in LDS as PACKED (hi | lo<<16) u32, pad 20 (proven).
// R22: dec2m interp writes vectorized (reg-accumulate + ds_write_b128).
// R23: dec3 s_up chunk-parity layout (conflicts 16.8M -> 10.1M).  FINAL.
// R24 (min-waves 5 on dec3) regressed: occupancy was grid-limited (1024
// blocks = 4/CU), bound only squeezed VGPR.  Reverted to min-waves 4.
// ---------------------------------------------------------------------------

template<int ACT> __device__ __forceinline__ float actf(float x){
  if (ACT == 1) return x > 0.f ? x : 0.01f * x;   // leaky relu, slope .01
  if (ACT == 2) return fmaxf(x, 0.f);             // relu
  return x;
}

typedef __bf16 bf16x8 __attribute__((ext_vector_type(8)));
typedef float f32x16 __attribute__((ext_vector_type(16)));
typedef unsigned int u32x4v __attribute__((ext_vector_type(4)));

__device__ __forceinline__ unsigned f2bf(unsigned u){   // RTNE f32->bf16 bits
  return (u + 0x7fffu + ((u >> 16) & 1u)) >> 16;
}

// ---------------- weight prep: f32 [64co][64ci][3][3] -> hi/lo bf16 --------
__global__ __launch_bounds__(256) void k_wprep(
    const float* __restrict__ w, unsigned short* __restrict__ wh,
    unsigned short* __restrict__ wl) {
  int i = blockIdx.x * 256 + threadIdx.x;           // 36864 = 4g*9tap*2*32*16
  if (i >= 36864) return;
  int ci16 = i & 15, co = (i >> 4) & 31, cot = (i >> 9) & 1;
  int rest = i >> 10, tap = rest % 9, g = rest / 9;
  float v = w[(cot * 32 + co) * 576 + (g * 16 + ci16) * 9 + tap];
  unsigned hi = f2bf(__float_as_uint(v));
  float lf = v - __uint_as_float(hi << 16);
  unsigned lo = f2bf(__float_as_uint(lf));
  wh[i] = (unsigned short)hi;
  wl[i] = (unsigned short)lo;
}

// ---------------- weight prep for dec2: f32 [32co][64ci][3][3] -------------
__global__ __launch_bounds__(256) void k_wprep2(
    const float* __restrict__ w, unsigned short* __restrict__ wh,
    unsigned short* __restrict__ wl) {
  int i = blockIdx.x * 256 + threadIdx.x;           // 18432 = 4g*9tap*32*16
  if (i >= 18432) return;
  int ci16 = i & 15, co = (i >> 4) & 31;
  int rest = i >> 9, tap = rest % 9, g = rest / 9;
  float v = w[co * 576 + (g * 16 + ci16) * 9 + tap];
  unsigned hi = f2bf(__float_as_uint(v));
  float lf = v - __uint_as_float(hi << 16);
  unsigned lo = f2bf(__float_as_uint(lf));
  wh[i] = (unsigned short)hi;
  wl[i] = (unsigned short)lo;
}

// ---------------- weight prep for enc2: f32 [64co][32ci][4][4] -------------
__global__ __launch_bounds__(256) void k_wprep_e2(
    const float* __restrict__ w, unsigned short* __restrict__ wh,
    unsigned short* __restrict__ wl) {
  int i = blockIdx.x * 256 + threadIdx.x;           // 32768 = 2g*16tap*2*32*16
  if (i >= 32768) return;
  int ci16 = i & 15, co = (i >> 4) & 31, cot = (i >> 9) & 1;
  int rest = i >> 10, tap = rest & 15, g = rest >> 4;
  float v = w[(cot * 32 + co) * 512 + (g * 16 + ci16) * 16 + tap];
  unsigned hi = f2bf(__float_as_uint(v));
  float lf = v - __uint_as_float(hi << 16);
  unsigned lo = f2bf(__float_as_uint(lf));
  wh[i] = (unsigned short)hi;
  wl[i] = (unsigned short)lo;
}

// ---------------- codebook prep for VQ MFMA: fragment-ordered hi/lo --------
__global__ __launch_bounds__(256) void k_cbprep_m(
    const float* __restrict__ cb, unsigned short* __restrict__ ch,
    unsigned short* __restrict__ cl_) {
  int i = blockIdx.x * 256 + threadIdx.x;           // 32768 = 16ct*4s*32*16
  if (i >= 32768) return;
  int ci16 = i & 15, cc = (i >> 4) & 31, ct4s = i >> 9;
  int s = ct4s & 3, ct = ct4s >> 2;
  float v = cb[(ct * 32 + cc) * 64 + s * 16 + ci16];
  unsigned hi = f2bf(__float_as_uint(v));
  float lf = v - __uint_as_float(hi << 16);
  unsigned lo = f2bf(__float_as_uint(lf));
  ch[i] = (unsigned short)hi;
  cl_[i] = (unsigned short)lo;
}

// ---------------- weight prep for 1x1: f32 [64co][64ci] --------------------
__global__ __launch_bounds__(256) void k_wprep_1x1(
    const float* __restrict__ w, unsigned short* __restrict__ wh,
    unsigned short* __restrict__ wl) {
  int i = blockIdx.x * 256 + threadIdx.x;           // 4096 = 2ct*4s*32*16
  if (i >= 4096) return;
  int ci16 = i & 15, cc = (i >> 4) & 31, s = (i >> 9) & 3, ct = i >> 11;
  float v = w[(ct * 32 + cc) * 64 + s * 16 + ci16];
  unsigned hi = f2bf(__float_as_uint(v));
  float lf = v - __uint_as_float(hi << 16);
  unsigned lo = f2bf(__float_as_uint(lf));
  wh[i] = (unsigned short)hi;
  wl[i] = (unsigned short)lo;
}

// ---------------- codebook squared norms -----------------------------------
__global__ __launch_bounds__(256) void k_cbnorm(const float* __restrict__ cb,
                                                float* __restrict__ nrm) {
  int c = blockIdx.x * 256 + threadIdx.x;
  if (c < 512) {
    float s = 0.f;
    for (int k = 0; k < 64; ++k) { float v = cb[c * 64 + k]; s = fmaf(v, v, s); }
    nrm[c] = s;
  }
}

// ---------------- enc1: 1->32, 4x4 s2 p1, 128->64, lrelu (LDS-staged) ------
__global__ __launch_bounds__(256) void k_enc1m(
    const float* __restrict__ in, const float* __restrict__ w,
    const float* __restrict__ b, float* __restrict__ out) {
  int n = blockIdx.x >> 3, y0 = (blockIdx.x & 7) * 8;
  int t = threadIdx.x;
  __shared__ float s_in[18 * 2 * 66];   // [r][parity][col/2], cols -1..128
  __shared__ float s_w[512];
  __shared__ float s_b[32];
  const float* ip = in + n * 16384;
  for (int i = t; i < 18 * 130; i += 256) {
    int r = i / 130, c = i - r * 130;
    int iy = 2 * y0 - 1 + r, ix = c - 1;
    float v = 0.f;
    if ((unsigned)iy < 128u && (unsigned)ix < 128u) v = ip[iy * 128 + ix];
    s_in[(r * 2 + (c & 1)) * 66 + (c >> 1)] = v;
  }
  for (int i = t; i < 512; i += 256) s_w[i] = w[i];
  if (t < 32) s_b[t] = b[t];
  __syncthreads();
  int ox = t & 63, wv = t >> 6;
#pragma unroll
  for (int rr = 0; rr < 2; ++rr) {
    int oyl = wv * 2 + rr;
    float x[16];
#pragma unroll
    for (int ky = 0; ky < 4; ++ky) {
      int r = 2 * oyl + ky;
#pragma unroll
      for (int kx = 0; kx < 4; ++kx) {
        x[ky * 4 + kx] = s_in[(r * 2 + (kx & 1)) * 66 + ox + (kx >> 1)];
      }
    }
    int obase = (n * 32) * 4096 + (y0 + oyl) * 64 + ox;
    for (int co = 0; co < 32; ++co) {
      float acc = s_b[co];
      const float* wr = &s_w[co * 16];
#pragma unroll
      for (int k = 0; k < 16; ++k) acc = fmaf(x[k], wr[k], acc);
      out[obase + co * 4096] = actf<1>(acc);
    }
  }
}

// ---------------- 3x3 64->64 stride1 pad1 @32x32 via MFMA ------------------
template<int ACT, bool BIAS>
__global__ __launch_bounds__(256, 3) void k_conv3m(
    const float* __restrict__ in, const unsigned short* __restrict__ wh,
    const unsigned short* __restrict__ wl, const float* __restrict__ bias,
    float* __restrict__ out) {
  int n = blockIdx.x >> 2, y0 = (blockIdx.x & 3) * 8;
  int t = threadIdx.x;
  int lane = t & 63, wv = t >> 6;
  int cot = wv & 1, rgroup = wv >> 1;
  int cc = lane & 31, h = lane >> 5;

  __shared__ __align__(16) unsigned int s_x[6800];   // [10 r][34 c][pad 20 ci]

  const uint4* wh4 = reinterpret_cast<const uint4*>(wh);
  const uint4* wl4 = reinterpret_cast<const uint4*>(wl);

  f32x16 acc[4];
#pragma unroll
  for (int r = 0; r < 4; ++r)
#pragma unroll
    for (int j = 0; j < 16; ++j) acc[r][j] = 0.f;

  for (int g = 0; g < 4; ++g) {
    if (g) __syncthreads();
    for (int i = t; i < 5440; i += 256) {
      int c = i % 34; int rem = i / 34; int r = rem % 10; int ci = rem / 10;
      int row = y0 - 1 + r, col = c - 1;
      float v = 0.f;
      if ((unsigned)row < 32u && (unsigned)col < 32u)
        v = in[(n * 64 + g * 16 + ci) * 1024 + row * 32 + col];
      unsigned hi = f2bf(__float_as_uint(v));
      float lf = v - __uint_as_float(hi << 16);
      unsigned lo = f2bf(__float_as_uint(lf));
      s_x[(r * 34 + c) * 20 + ci] = hi | (lo << 16);
    }
    __syncthreads();

#pragma unroll
    for (int kx = 0; kx < 3; ++kx) {
      bf16x8 Ah[3], Al[3];
#pragma unroll
      for (int ky = 0; ky < 3; ++ky) {
        int wi = ((g * 9 + ky * 3 + kx) * 2 + cot) * 64 + cc * 2 + h;
        Ah[ky] = __builtin_bit_cast(bf16x8, wh4[wi]);
        Al[ky] = __builtin_bit_cast(bf16x8, wl4[wi]);
      }
#pragma unroll
      for (int ir6 = 0; ir6 < 6; ++ir6) {
        int ir = rgroup * 4 + ir6;
        const uint4* xp = reinterpret_cast<const uint4*>(
            &s_x[(ir * 34 + cc + kx) * 20 + (h << 3)]);
        uint4 qa = xp[0], qb = xp[1];
        u32x4v bh, bl;
        bh[0] = (qa.x & 0xffffu) | (qa.y << 16);
        bh[1] = (qa.z & 0xffffu) | (qa.w << 16);
        bh[2] = (qb.x & 0xffffu) | (qb.y << 16);
        bh[3] = (qb.z & 0xffffu) | (qb.w << 16);
        bl[0] = (qa.x >> 16) | (qa.y & 0xffff0000u);
        bl[1] = (qa.z >> 16) | (qa.w & 0xffff0000u);
        bl[2] = (qb.x >> 16) | (qb.y & 0xffff0000u);
        bl[3] = (qb.z >> 16) | (qb.w & 0xffff0000u);
        bf16x8 Bh = __builtin_bit_cast(bf16x8, bh);
        bf16x8 Bl = __builtin_bit_cast(bf16x8, bl);
#pragma unroll
        for (int ky = 0; ky < 3; ++ky) {
          int rr = ir6 - ky;
          if (rr < 0 || rr > 3) continue;
          acc[rr] = __builtin_amdgcn_mfma_f32_32x32x16_bf16(Ah[ky], Bh, acc[rr], 0, 0, 0);
          acc[rr] = __builtin_amdgcn_mfma_f32_32x32x16_bf16(Ah[ky], Bl, acc[rr], 0, 0, 0);
          acc[rr] = __builtin_amdgcn_mfma_f32_32x32x16_bf16(Al[ky], Bh, acc[rr], 0, 0, 0);
        }
      }
    }
  }

  float bvv[16];
#pragma unroll
  for (int reg = 0; reg < 16; ++reg) {
    int row = (reg & 3) + 8 * (reg >> 2) + 4 * h;
    bvv[reg] = BIAS ? bias[cot * 32 + row] : 0.f;
  }
#pragma unroll
  for (int rr = 0; rr < 4; ++rr) {
    int y = y0 + rgroup * 4 + rr;
#pragma unroll
    for (int reg = 0; reg < 16; ++reg) {
      int row = (reg & 3) + 8 * (reg >> 2) + 4 * h;
      int co = cot * 32 + row;
      float v = acc[rr][reg] + bvv[reg];
      out[(n * 64 + co) * 1024 + y * 32 + cc] = actf<ACT>(v);
    }
  }
}

// ---------------- enc2: 32->64, 4x4 s2 p1, 64->32 via MFMA -----------------
__global__ __launch_bounds__(256, 2) void k_enc2m(
    const float* __restrict__ in, const unsigned short* __restrict__ wh,
    const unsigned short* __restrict__ wl, const float* __restrict__ bias,
    float* __restrict__ out) {
  int n = blockIdx.x >> 3, y0 = (blockIdx.x & 7) * 4;
  int t = threadIdx.x;
  int lane = t & 63, wv = t >> 6;
  int cot = wv & 1, rg = wv >> 1;
  int cc = lane & 31, h = lane >> 5;

  __shared__ __align__(16) unsigned int s_x[13200];  // [10][2][33][20]

  const uint4* wh4 = reinterpret_cast<const uint4*>(wh);
  const uint4* wl4 = reinterpret_cast<const uint4*>(wl);

  f32x16 acc[2];
#pragma unroll
  for (int r = 0; r < 2; ++r)
#pragma unroll
    for (int j = 0; j < 16; ++j) acc[r][j] = 0.f;

  for (int g = 0; g < 2; ++g) {
    if (g) __syncthreads();
    for (int i = t; i < 10560; i += 256) {
      int ci = i / 660, rem = i - ci * 660;
      int r = rem / 66, c = rem - r * 66;
      int row = 2 * y0 - 1 + r, icol = c - 1;
      float v = 0.f;
      if ((unsigned)row < 64u && (unsigned)icol < 64u)
        v = in[((n * 32 + g * 16 + ci) * 64 + row) * 64 + icol];
      unsigned hi = f2bf(__float_as_uint(v));
      float lf = v - __uint_as_float(hi << 16);
      unsigned lo = f2bf(__float_as_uint(lf));
      int p = icol & 1;
      int idx = (icol + p) >> 1;
      s_x[((r * 2 + p) * 33 + idx) * 20 + ci] = hi | (lo << 16);
    }
    __syncthreads();

#pragma unroll
    for (int kx = 0; kx < 4; ++kx) {
      bf16x8 Ah[4], Al[4];
#pragma unroll
      for (int ky = 0; ky < 4; ++ky) {
        int wi = ((g * 16 + ky * 4 + kx) * 2 + cot) * 64 + cc * 2 + h;
        Ah[ky] = __builtin_bit_cast(bf16x8, wh4[wi]);
        Al[ky] = __builtin_bit_cast(bf16x8, wl4[wi]);
      }
      int p = (kx + 1) & 1;
      int idx = cc + (kx >> 1);
#pragma unroll
      for (int ir6 = 0; ir6 < 6; ++ir6) {
        int r = rg * 4 + ir6;
        const uint4* xp = reinterpret_cast<const uint4*>(
            &s_x[((r * 2 + p) * 33 + idx) * 20 + (h << 3)]);
        uint4 qa = xp[0], qb = xp[1];
        u32x4v bh, bl;
        bh[0] = (qa.x & 0xffffu) | (qa.y << 16);
        bh[1] = (qa.z & 0xffffu) | (qa.w << 16);
        bh[2] = (qb.x & 0xffffu) | (qb.y << 16);
        bh[3] = (qb.z & 0xffffu) | (qb.w << 16);
        bl[0] = (qa.x >> 16) | (qa.y & 0xffff0000u);
        bl[1] = (qa.z >> 16) | (qa.w & 0xffff0000u);
        bl[2] = (qb.x >> 16) | (qb.y & 0xffff0000u);
        bl[3] = (qb.z >> 16) | (qb.w & 0xffff0000u);
        bf16x8 Bh = __builtin_bit_cast(bf16x8, bh);
        bf16x8 Bl = __builtin_bit_cast(bf16x8, bl);
#pragma unroll
        for (int rr = 0; rr < 2; ++rr) {
          int ky = ir6 - 2 * rr;
          if (ky < 0 || ky > 3) continue;
          acc[rr] = __builtin_amdgcn_mfma_f32_32x32x16_bf16(Ah[ky], Bh, acc[rr], 0, 0, 0);
          acc[rr] = __builtin_amdgcn_mfma_f32_32x32x16_bf16(Ah[ky], Bl, acc[rr], 0, 0, 0);
          acc[rr] = __builtin_amdgcn_mfma_f32_32x32x16_bf16(Al[ky], Bh, acc[rr], 0, 0, 0);
        }
      }
    }
  }

#pragma unroll
  for (int rr = 0; rr < 2; ++rr) {
    int oy = y0 + rg * 2 + rr;
#pragma unroll
    for (int reg = 0; reg < 16; ++reg) {
      int corow = (reg & 3) + 8 * (reg >> 2) + 4 * h;
      int co = cot * 32 + corow;
      float v = acc[rr][reg] + bias[co];
      out[(n * 64 + co) * 1024 + oy * 32 + cc] = actf<1>(v);
    }
  }
}

// ---------------- 1x1 64->64 via MFMA (vq2m-machinery subset) --------------
template<int ACT, bool BIAS, bool ADD>
__global__ __launch_bounds__(256, 2) void k_1x1m(
    const float* __restrict__ in, const unsigned short* __restrict__ wh,
    const unsigned short* __restrict__ wl, const float* __restrict__ bias,
    const float* __restrict__ add, float* __restrict__ out) {
  int bid = blockIdx.x;                  // 2048 = 128 n x 16 s-tiles
  int n = bid >> 4, s0 = (bid & 15) << 6;
  int t = threadIdx.x;
  int lane = t & 63, wv = t >> 6;
  int cc = lane & 31, h = lane >> 5;
  int ct = wv & 1, pt = wv >> 1;

  __shared__ __align__(16) unsigned int s_pk[5120];   // [4 s][64 pos][pad 20]

  for (int i = t; i < 4096; i += 256) {
    int pos = i & 63, k = i >> 6;
    float v = in[(n * 64 + k) * 1024 + s0 + pos];
    unsigned hi = f2bf(__float_as_uint(v));
    float lf = v - __uint_as_float(hi << 16);
    unsigned lo = f2bf(__float_as_uint(lf));
    s_pk[(((k >> 4) * 64) + pos) * 20 + (k & 15)] = hi | (lo << 16);
  }
  __syncthreads();

  const uint4* ah4 = reinterpret_cast<const uint4*>(wh);
  const uint4* al4 = reinterpret_cast<const uint4*>(wl);

  f32x16 acc;
#pragma unroll
  for (int j = 0; j < 16; ++j) acc[j] = 0.f;

#pragma unroll
  for (int s = 0; s < 4; ++s) {
    const uint4* xp = reinterpret_cast<const uint4*>(
        &s_pk[((s * 64) + pt * 32 + cc) * 20 + (h << 3)]);
    uint4 qa = xp[0], qb = xp[1];
    u32x4v bh, bl;
    bh[0] = (qa.x & 0xffffu) | (qa.y << 16);
    bh[1] = (qa.z & 0xffffu) | (qa.w << 16);
    bh[2] = (qb.x & 0xffffu) | (qb.y << 16);
    bh[3] = (qb.z & 0xffffu) | (qb.w << 16);
    bl[0] = (qa.x >> 16) | (qa.y & 0xffff0000u);
    bl[1] = (qa.z >> 16) | (qa.w & 0xffff0000u);
    bl[2] = (qb.x >> 16) | (qb.y & 0xffff0000u);
    bl[3] = (qb.z >> 16) | (qb.w & 0xffff0000u);
    bf16x8 Bh = __builtin_bit_cast(bf16x8, bh);
    bf16x8 Bl = __builtin_bit_cast(bf16x8, bl);
    int wi = (ct * 4 + s) * 64 + cc * 2 + h;
    bf16x8 Ah = __builtin_bit_cast(bf16x8, ah4[wi]);
    bf16x8 Al = __builtin_bit_cast(bf16x8, al4[wi]);
    acc = __builtin_amdgcn_mfma_f32_32x32x16_bf16(Ah, Bh, acc, 0, 0, 0);
    acc = __builtin_amdgcn_mfma_f32_32x32x16_bf16(Ah, Bl, acc, 0, 0, 0);
    acc = __builtin_amdgcn_mfma_f32_32x32x16_bf16(Al, Bh, acc, 0, 0, 0);
  }

  int pos = pt * 32 + cc;
#pragma unroll
  for (int reg = 0; reg < 16; ++reg) {
    int row = (reg & 3) + 8 * (reg >> 2) + 4 * h;
    int co = ct * 32 + row;
    float v = acc[reg] + (BIAS ? bias[co] : 0.f);
    int gi = (n * 64 + co) * 1024 + s0 + pos;
    if (ADD) v += add[gi];
    out[gi] = actf<ACT>(v);
  }
}

// ---------------- VQ via MFMA: dist GEMM + argmin + q + loss ---------------
__global__ __launch_bounds__(256, 2) void k_vq2m(
    const float* __restrict__ lat, const unsigned short* __restrict__ cbh,
    const unsigned short* __restrict__ cbl, const float* __restrict__ cb,
    const float* __restrict__ nrm, float* __restrict__ q,
    double* __restrict__ part) {
  int bid = blockIdx.x;                  // 2048 = 128 n x 16 s-tiles
  int n = bid >> 4, s0 = (bid & 15) << 6;
  int t = threadIdx.x;
  int lane = t & 63, wv = t >> 6;
  int cc = lane & 31, h = lane >> 5;

  __shared__ __align__(16) unsigned int s_pk[5120];   // [4 s][64 pos][pad 20]
  __shared__ float s_lat_f[4096];                     // [k][pos]
  __shared__ float s_nrm[512];
  __shared__ float s_rd[512];                         // [pos][8 slots]
  __shared__ int   s_ri[512];
  __shared__ int   s_sel[64];
  __shared__ double s_r[256];

  for (int i = t; i < 4096; i += 256) {
    int pos = i & 63, k = i >> 6;
    float v = lat[(n * 64 + k) * 1024 + s0 + pos];
    s_lat_f[k * 64 + pos] = v;
    unsigned hi = f2bf(__float_as_uint(v));
    float lf = v - __uint_as_float(hi << 16);
    unsigned lo = f2bf(__float_as_uint(lf));
    s_pk[(((k >> 4) * 64) + pos) * 20 + (k & 15)] = hi | (lo << 16);
  }
  for (int i = t; i < 512; i += 256) s_nrm[i] = nrm[i];
  __syncthreads();

  const uint4* ah4 = reinterpret_cast<const uint4*>(cbh);
  const uint4* al4 = reinterpret_cast<const uint4*>(cbl);

  float best[2] = {3.4e38f, 3.4e38f};
  int bidx[2] = {0, 0};

#pragma unroll
  for (int ip = 0; ip < 2; ++ip) {
    f32x16 acc[2][2];
#pragma unroll
    for (int a = 0; a < 2; ++a)
#pragma unroll
      for (int b = 0; b < 2; ++b)
#pragma unroll
        for (int j = 0; j < 16; ++j) acc[a][b][j] = 0.f;

#pragma unroll
    for (int s = 0; s < 4; ++s) {
      bf16x8 Bh[2], Bl[2];
#pragma unroll
      for (int pt = 0; pt < 2; ++pt) {
        const uint4* xp = reinterpret_cast<const uint4*>(
            &s_pk[((s * 64) + pt * 32 + cc) * 20 + (h << 3)]);
        uint4 qa = xp[0], qb = xp[1];
        u32x4v bh, bl;
        bh[0] = (qa.x & 0xffffu) | (qa.y << 16);
        bh[1] = (qa.z & 0xffffu) | (qa.w << 16);
        bh[2] = (qb.x & 0xffffu) | (qb.y << 16);
        bh[3] = (qb.z & 0xffffu) | (qb.w << 16);
        bl[0] = (qa.x >> 16) | (qa.y & 0xffff0000u);
        bl[1] = (qa.z >> 16) | (qa.w & 0xffff0000u);
        bl[2] = (qb.x >> 16) | (qb.y & 0xffff0000u);
        bl[3] = (qb.z >> 16) | (qb.w & 0xffff0000u);
        Bh[pt] = __builtin_bit_cast(bf16x8, bh);
        Bl[pt] = __builtin_bit_cast(bf16x8, bl);
      }
#pragma unroll
      for (int it2 = 0; it2 < 2; ++it2) {
        int ct = wv * 4 + ip * 2 + it2;
        int wi = (ct * 4 + s) * 64 + cc * 2 + h;
        bf16x8 Ah = __builtin_bit_cast(bf16x8, ah4[wi]);
        bf16x8 Al = __builtin_bit_cast(bf16x8, al4[wi]);
#pragma unroll
        for (int pt = 0; pt < 2; ++pt) {
          acc[it2][pt] = __builtin_amdgcn_mfma_f32_32x32x16_bf16(Ah, Bh[pt], acc[it2][pt], 0, 0, 0);
          acc[it2][pt] = __builtin_amdgcn_mfma_f32_32x32x16_bf16(Ah, Bl[pt], acc[it2][pt], 0, 0, 0);
          acc[it2][pt] = __builtin_amdgcn_mfma_f32_32x32x16_bf16(Al, Bh[pt], acc[it2][pt], 0, 0, 0);
        }
      }
    }

#pragma unroll
    for (int it2 = 0; it2 < 2; ++it2) {
      int ct = wv * 4 + ip * 2 + it2;
#pragma unroll
      for (int pt = 0; pt < 2; ++pt) {
#pragma unroll
        for (int reg = 0; reg < 16; ++reg) {
          int code = ct * 32 + (reg & 3) + 8 * (reg >> 2) + 4 * h;
          float d = fmaf(-2.f, acc[it2][pt][reg], s_nrm[code]);
          if (d < best[pt] || (d == best[pt] && code < bidx[pt])) {
            best[pt] = d; bidx[pt] = code;
          }
        }
      }
    }
  }

#pragma unroll
  for (int pt = 0; pt < 2; ++pt) {
    int pos = pt * 32 + cc;
    s_rd[pos * 8 + wv * 2 + h] = best[pt];
    s_ri[pos * 8 + wv * 2 + h] = bidx[pt];
  }
  __syncthreads();
  if (t < 64) {
    float bd = s_rd[t * 8]; int bi = s_ri[t * 8];
#pragma unroll
    for (int m = 1; m < 8; ++m) {
      float d = s_rd[t * 8 + m]; int ii = s_ri[t * 8 + m];
      if (d < bd || (d == bd && ii < bi)) { bd = d; bi = ii; }
    }
    s_sel[t] = bi;
  }
  __syncthreads();

  int pos = t & 63, dg = t >> 6;
  int bsel = s_sel[pos];
  const float* cw = cb + bsel * 64 + dg * 16;
  float psum = 0.f;
#pragma unroll
  for (int kk = 0; kk < 16; ++kk) {
    int k = dg * 16 + kk;
    float cv = cw[kk];
    float l = s_lat_f[k * 64 + pos];
    float df = cv - l;
    psum = fmaf(df, df, psum);
    q[(n * 64 + k) * 1024 + s0 + pos] = cv;
  }
  s_r[t] = (double)psum;
  __syncthreads();
  for (int str = 128; str > 0; str >>= 1) {
    if (t < str) s_r[t] += s_r[t + str];
    __syncthreads();
  }
  if (t == 0) part[bid] = s_r[0];
}

// ---------------- dec2: up2x(ac) + 3x3 64->32 + lrelu, via MFMA ------------
// R22: interp packs into registers (static-indexed, fully unrolled), then
// 4+4 ds_write_b128 per thread per g (was 32 scalar ds_write_b32).
__global__ __launch_bounds__(256, 3) void k_dec2m(
    const float* __restrict__ in, const unsigned short* __restrict__ wh,
    const unsigned short* __restrict__ wl, const float* __restrict__ bias,
    float* __restrict__ out) {
  int n = blockIdx.x >> 4, y0 = (blockIdx.x & 15) * 4;
  int t = threadIdx.x;
  int lane = t & 63, wv = t >> 6;
  int xh = wv & 1, rg = wv >> 1;
  int cc = lane & 31, h = lane >> 5;

  __shared__ __align__(16) unsigned int s_x[6 * 66 * 20];   // packed up-tile
  __shared__ float s_src[16 * 165];                         // [ci][5r][33]
  __shared__ float2 s_wmy[6];
  __shared__ int2   s_ryp[6];
  __shared__ float2 s_wmx[66];
  __shared__ int2   s_rxp[66];

  const float sc = 31.0f / 63.0f;
  int r0 = (y0 == 0) ? 0 : (int)floorf((float)(y0 - 1) * sc);

  if (t < 6) {
    int uy = y0 - 1 + t;
    int uyc = min(max(uy, 0), 63);
    float sy = (float)uyc * sc;
    int iy0 = (int)floorf(sy);
    s_wmy[t] = make_float2(sy - (float)iy0, ((unsigned)uy < 64u) ? 1.f : 0.f);
    s_ryp[t] = make_int2(iy0 - r0, min(iy0 + 1, 31) - r0);
  }
  int xc = t - 64;
  if (xc >= 0 && xc < 66) {
    int ux = xc - 1;
    int uxc = min(max(ux, 0), 63);
    float sx = (float)uxc * sc;
    int ix0 = (int)floorf(sx);
    s_wmx[xc] = make_float2(sx - (float)ix0, ((unsigned)ux < 64u) ? 1.f : 0.f);
    s_rxp[xc] = make_int2(ix0, min(ix0 + 1, 31));
  }

  // stage g=0 src: 16 ci x 5 rows x 32 cols
  for (int i = t; i < 2560; i += 256) {
    int ci = i / 160, rem = i - ci * 160;
    int rr = rem >> 5, c = rem & 31;
    int row = r0 + rr;
    s_src[ci * 165 + rr * 33 + c] =
        (row < 32) ? in[(n * 64 + ci) * 1024 + row * 32 + c] : 0.f;
  }
  __syncthreads();

  // slot setup: slot 0 (pos = t) always valid; slot 1 (pos = t+256) for t<140
  int so00[2], so01[2], so10[2], so11[2], spos[2];
  float swy[2], swx[2], smm[2];
  bool sval1;
  {
    int p = t;
    int u = p / 66, c = p - u * 66;
    float2 wmy = s_wmy[u]; int2 ry = s_ryp[u];
    float2 wmx = s_wmx[c]; int2 rx = s_rxp[c];
    swy[0] = wmy.x; swx[0] = wmx.x; smm[0] = wmy.y * wmx.y;
    so00[0] = ry.x * 33 + rx.x; so01[0] = ry.x * 33 + rx.y;
    so10[0] = ry.y * 33 + rx.x; so11[0] = ry.y * 33 + rx.y;
    spos[0] = p * 20;
  }
  {
    int pos1 = t + 256;
    sval1 = pos1 < 396;
    int p = sval1 ? pos1 : 0;
    int u = p / 66, c = p - u * 66;
    float2 wmy = s_wmy[u]; int2 ry = s_ryp[u];
    float2 wmx = s_wmx[c]; int2 rx = s_rxp[c];
    swy[1] = wmy.x; swx[1] = wmx.x; smm[1] = wmy.y * wmx.y;
    so00[1] = ry.x * 33 + rx.x; so01[1] = ry.x * 33 + rx.y;
    so10[1] = ry.y * 33 + rx.x; so11[1] = ry.y * 33 + rx.y;
    spos[1] = p * 20;
  }

  const uint4* wh4 = reinterpret_cast<const uint4*>(wh);
  const uint4* wl4 = reinterpret_cast<const uint4*>(wl);

  f32x16 acc[2];
#pragma unroll
  for (int r = 0; r < 2; ++r)
#pragma unroll
    for (int j = 0; j < 16; ++j) acc[r][j] = 0.f;

  for (int g = 0; g < 4; ++g) {
    // ---- interp + split-pack into registers (static indices) ----
    unsigned pk0[16], pk1[16];
#pragma unroll
    for (int ci = 0; ci < 16; ++ci) {
      const float* sp = s_src + ci * 165;
      {
        float a00 = sp[so00[0]], a01 = sp[so01[0]];
        float a10 = sp[so10[0]], a11 = sp[so11[0]];
        float h0 = fmaf(a10 - a00, swy[0], a00);
        float h1 = fmaf(a11 - a01, swy[0], a01);
        float v = smm[0] * fmaf(h1 - h0, swx[0], h0);
        __bf16 hb = (__bf16)v;
        float hf = (float)hb;
        __bf16 lb = (__bf16)(v - hf);
        pk0[ci] = (unsigned)__builtin_bit_cast(unsigned short, hb)
                | ((unsigned)__builtin_bit_cast(unsigned short, lb) << 16);
      }
      {
        float a00 = sp[so00[1]], a01 = sp[so01[1]];
        float a10 = sp[so10[1]], a11 = sp[so11[1]];
        float h0 = fmaf(a10 - a00, swy[1], a00);
        float h1 = fmaf(a11 - a01, swy[1], a01);
        float v = smm[1] * fmaf(h1 - h0, swx[1], h0);
        __bf16 hb = (__bf16)v;
        float hf = (float)hb;
        __bf16 lb = (__bf16)(v - hf);
        pk1[ci] = (unsigned)__builtin_bit_cast(unsigned short, hb)
                | ((unsigned)__builtin_bit_cast(unsigned short, lb) << 16);
      }
    }
    // ---- vectorized LDS writes: 4 (+4) x ds_write_b128 ----
#pragma unroll
    for (int qd = 0; qd < 4; ++qd) {
      *reinterpret_cast<uint4*>(&s_x[spos[0] + qd * 4]) =
          make_uint4(pk0[qd * 4], pk0[qd * 4 + 1], pk0[qd * 4 + 2], pk0[qd * 4 + 3]);
    }
    if (sval1) {
#pragma unroll
      for (int qd = 0; qd < 4; ++qd) {
        *reinterpret_cast<uint4*>(&s_x[spos[1] + qd * 4]) =
            make_uint4(pk1[qd * 4], pk1[qd * 4 + 1], pk1[qd * 4 + 2], pk1[qd * 4 + 3]);
      }
    }
    __syncthreads();

    // ---- stage next src group (overlaps MFMA) ----
    if (g < 3) {
      int ci0 = (g + 1) * 16;
      for (int i = t; i < 2560; i += 256) {
        int ci = i / 160, rem = i - ci * 160;
        int rr = rem >> 5, c = rem & 31;
        int row = r0 + rr;
        s_src[ci * 165 + rr * 33 + c] =
            (row < 32) ? in[(n * 64 + ci0 + ci) * 1024 + row * 32 + c] : 0.f;
      }
    }

    // ---- MFMA ----
#pragma unroll
    for (int kx = 0; kx < 3; ++kx) {
      bf16x8 Ah[3], Al[3];
#pragma unroll
      for (int ky = 0; ky < 3; ++ky) {
        int wi = (g * 9 + ky * 3 + kx) * 64 + cc * 2 + h;
        Ah[ky] = __builtin_bit_cast(bf16x8, wh4[wi]);
        Al[ky] = __builtin_bit_cast(bf16x8, wl4[wi]);
      }
#pragma unroll
      for (int u6 = 0; u6 < 4; ++u6) {
        int u = rg * 2 + u6;
        const uint4* xp = reinterpret_cast<const uint4*>(
            &s_x[(u * 66 + xh * 32 + cc + kx) * 20 + (h << 3)]);
        uint4 qa = xp[0], qb = xp[1];
        u32x4v bh, bl;
        bh[0] = (qa.x & 0xffffu) | (qa.y << 16);
        bh[1] = (qa.z & 0xffffu) | (qa.w << 16);
        bh[2] = (qb.x & 0xffffu) | (qb.y << 16);
        bh[3] = (qb.z & 0xffffu) | (qb.w << 16);
        bl[0] = (qa.x >> 16) | (qa.y & 0xffff0000u);
        bl[1] = (qa.z >> 16) | (qa.w & 0xffff0000u);
        bl[2] = (qb.x >> 16) | (qb.y & 0xffff0000u);
        bl[3] = (qb.z >> 16) | (qb.w & 0xffff0000u);
        bf16x8 Bh = __builtin_bit_cast(bf16x8, bh);
        bf16x8 Bl = __builtin_bit_cast(bf16x8, bl);
#pragma unroll
        for (int ky = 0; ky < 3; ++ky) {
          int rr = u6 - ky;
          if (rr < 0 || rr > 1) continue;
          acc[rr] = __builtin_amdgcn_mfma_f32_32x32x16_bf16(Ah[ky], Bh, acc[rr], 0, 0, 0);
          acc[rr] = __builtin_amdgcn_mfma_f32_32x32x16_bf16(Ah[ky], Bl, acc[rr], 0, 0, 0);
          acc[rr] = __builtin_amdgcn_mfma_f32_32x32x16_bf16(Al[ky], Bh, acc[rr], 0, 0, 0);
        }
      }
    }
    __syncthreads();
  }

  float bvv[16];
#pragma unroll
  for (int reg = 0; reg < 16; ++reg) {
    int co = (reg & 3) + 8 * (reg >> 2) + 4 * h;
    bvv[reg] = bias[co];
  }
#pragma unroll
  for (int rr = 0; rr < 2; ++rr) {
    int y = y0 + rg * 2 + rr;
#pragma unroll
    for (int reg = 0; reg < 16; ++reg) {
      int co = (reg & 3) + 8 * (reg >> 2) + 4 * h;
      float v = acc[rr][reg] + bvv[reg];
      out[(n * 32 + co) * 4096 + y * 64 + xh * 32 + cc] = actf<1>(v);
    }
  }
}

// ---------------- loss finalize --------------------------------------------
__global__ __launch_bounds__(256) void k_loss(const double* __restrict__ part,
                                              float* __restrict__ out) {
  __shared__ double s[256];
  int t = threadIdx.x;
  double acc = 0.0;
  for (int i = t; i < 2048; i += 256) acc += part[i];
  s[t] = acc;
  __syncthreads();
  for (int str = 128; str > 0; str >>= 1) {
    if (t < str) s[t] += s[t + str];
    __syncthreads();
  }
  if (t == 0) {
    double mean = s[0] / 8388608.0;
    out[2097152] = (float)mean;
    out[2097153] = (float)(0.25 * mean);
  }
}

// ---------------- dec3: up2x(ac) + 3x3 32->1 + relu ------------------------
// FULL-WIDTH tiles: block = (n, 16-row strip), all 128 cols.
// R23 chunk-parity layout; min-waves 4 (R24's 5 regressed: grid-limited).
__global__ __launch_bounds__(256, 4) void k_dec3(
    const float* __restrict__ in, const float* __restrict__ w,
    const float* __restrict__ bias, float* __restrict__ out) {
  int bid = blockIdx.x;                  // 1024 = 128n * 8yT
  int n = bid >> 3, yT = bid & 7;
  int y0 = yT * 16;
  int t = threadIdx.x;
  int ty = t >> 4, xq = t & 15;          // 16 rows x 16 colgroups of 8

  __shared__ __align__(16) float s_up[2 * 18 * 136];  // [ci][18 u][34 chunks]
  __shared__ float s_src[2 * 11 * 66];   // [ci][11 r][64 c pad 66]
  __shared__ float s_w[288];
  __shared__ float2 s_wmy[18];
  __shared__ int2   s_ryp[18];
  __shared__ float2 s_wmx[130];
  __shared__ int2   s_rxp[130];

  const float sc = 63.0f / 127.0f;
  int r0 = (y0 == 0) ? 0 : (int)floorf((float)(y0 - 1) * sc);

  if (t < 18) {
    int uy = y0 - 1 + t;
    int uyc = min(max(uy, 0), 127);
    float sy = (float)uyc * sc;
    int iy0 = (int)floorf(sy);
    s_wmy[t] = make_float2(sy - (float)iy0, ((unsigned)uy < 128u) ? 1.f : 0.f);
    s_ryp[t] = make_int2(iy0 - r0, min(iy0 + 1, 63) - r0);
  }
  if (t < 130) {
    int ux = t - 1;
    int uxc = min(max(ux, 0), 127);
    float sx = (float)uxc * sc;
    int ix0 = (int)floorf(sx);
    s_wmx[t] = make_float2(sx - (float)ix0, ((unsigned)ux < 128u) ? 1.f : 0.f);
    s_rxp[t] = make_int2(ix0, min(ix0 + 1, 63));
  }
  for (int i = t; i < 288; i += 256) s_w[i] = w[i];

  float acc[8];
#pragma unroll
  for (int xx = 0; xx < 8; ++xx) acc[xx] = 0.f;

  // prologue stage g=0 (2 ci): aligned full-width rows
  for (int i = t; i < 2 * 11 * 64; i += 256) {
    int ci = i / 704, rem = i - ci * 704;
    int rr = rem >> 6, c = rem & 63;
    int row = r0 + rr;
    s_src[(ci * 11 + rr) * 66 + c] =
        (row < 64) ? in[((n * 32 + ci) * 64 + row) * 64 + c] : 0.f;
  }
  __syncthreads();

  for (int g = 0; g < 16; ++g) {
#pragma unroll
    for (int ci = 0; ci < 2; ++ci) {
      const float* sp = s_src + ci * 726;
      float* up = s_up + ci * 2448;      // 18 * 136
      for (int i = t; i < 2304; i += 256) {
        int u = i >> 7, c = i & 127;
        float2 wmy = s_wmy[u]; int2 ry = s_ryp[u];
        float2 wmx = s_wmx[c]; int2 rx = s_rxp[c];
        const float* r0p = sp + ry.x * 66;
        const float* r1p = sp + ry.y * 66;
        float a00 = r0p[rx.x], a01 = r0p[rx.y];
        float a10 = r1p[rx.x], a11 = r1p[rx.y];
        float h0 = fmaf(a10 - a00, wmy.x, a00);
        float h1 = fmaf(a11 - a01, wmy.x, a01);
        // chunk-parity position: k = c>>2; even -> k/2, odd -> 17 + k/2
        int cp = ((c & 4) ? (68 + ((c >> 3) << 2)) : ((c >> 3) << 2)) + (c & 3);
        up[u * 136 + cp] = (wmy.y * wmx.y) * fmaf(h1 - h0, wmx.x, h0);
      }
      if (t < 36) {
        int u = t >> 1, c = 128 + (t & 1);
        float2 wmy = s_wmy[u]; int2 ry = s_ryp[u];
        float2 wmx = s_wmx[c]; int2 rx = s_rxp[c];
        const float* r0p = sp + ry.x * 66;
        const float* r1p = sp + ry.y * 66;
        float a00 = r0p[rx.x], a01 = r0p[rx.y];
        float a10 = r1p[rx.x], a11 = r1p[rx.y];
        float h0 = fmaf(a10 - a00, wmy.x, a00);
        float h1 = fmaf(a11 - a01, wmy.x, a01);
        int cp = ((c & 4) ? (68 + ((c >> 3) << 2)) : ((c >> 3) << 2)) + (c & 3);
        up[u * 136 + cp] = (wmy.y * wmx.y) * fmaf(h1 - h0, wmx.x, h0);
      }
    }
    __syncthreads();

    if (g < 15) {
      int ci0 = (g + 1) * 2;
      for (int i = t; i < 2 * 11 * 64; i += 256) {
        int ci = i / 704, rem = i - ci * 704;
        int rr = rem >> 6, c = rem & 63;
        int row = r0 + rr;
        s_src[(ci * 11 + rr) * 66 + c] =
            (row < 64) ? in[((n * 32 + ci0 + ci) * 64 + row) * 64 + c] : 0.f;
      }
    }

    int ci0 = g * 2;
#pragma unroll
    for (int ci = 0; ci < 2; ++ci) {
#pragma unroll
      for (int ky = 0; ky < 3; ++ky) {
        int rbase = (ci * 18 + ty + ky) * 136;
        // chunks 2xq, 2xq+1, 2xq+2 -> float positions 4xq, 68+4xq, 4xq+4
        float4 q0 = *reinterpret_cast<const float4*>(&s_up[rbase + xq * 4]);
        float4 q1 = *reinterpret_cast<const float4*>(&s_up[rbase + 68 + xq * 4]);
        float4 q2 = *reinterpret_cast<const float4*>(&s_up[rbase + xq * 4 + 4]);
        float rv[12] = {q0.x, q0.y, q0.z, q0.w, q1.x, q1.y, q1.z, q1.w,
                        q2.x, q2.y, q2.z, q2.w};
#pragma unroll
        for (int kx = 0; kx < 3; ++kx) {
          float wv = s_w[(ci0 + ci) * 9 + ky * 3 + kx];
#pragma unroll
          for (int xx = 0; xx < 8; ++xx)
            acc[xx] = fmaf(rv[xx + kx], wv, acc[xx]);
        }
      }
    }
    __syncthreads();
  }
  float bv = bias[0];
  int base = n * 16384 + (y0 + ty) * 128 + xq * 8;
  float o[8];
#pragma unroll
  for (int xx = 0; xx < 8; ++xx) o[xx] = actf<2>(acc[xx] + bv);
  *reinterpret_cast<float4*>(&out[base]) = make_float4(o[0], o[1], o[2], o[3]);
  *reinterpret_cast<float4*>(&out[base + 4]) = make_float4(o[4], o[5], o[6], o[7]);
}

// ---------------------------------------------------------------------------
extern "C" void kernel_launch(void* const* d_in, const int* in_sizes, int n_in,
                              void* d_out, int out_size, void* d_ws, size_t ws_size,
                              hipStream_t stream) {
  (void)in_sizes; (void)n_in; (void)out_size; (void)ws_size;
  const float* x_in     = (const float*)d_in[0];
  const float* enc_w1   = (const float*)d_in[1];
  const float* enc_b1   = (const float*)d_in[2];
  const float* enc_w2   = (const float*)d_in[3];
  const float* enc_b2   = (const float*)d_in[4];
  const float* enc_w3   = (const float*)d_in[5];
  const float* enc_b3   = (const float*)d_in[6];
  const float* res_e_w1 = (const float*)d_in[7];
  const float* res_e_w2 = (const float*)d_in[8];
  const float* enc_w4   = (const float*)d_in[9];
  const float* enc_b4   = (const float*)d_in[10];
  const float* codebook = (const float*)d_in[11];
  const float* dec_w1   = (const float*)d_in[12];
  const float* dec_b1   = (const float*)d_in[13];
  const float* res_d_w1 = (const float*)d_in[14];
  const float* res_d_w2 = (const float*)d_in[15];
  const float* dec_w2   = (const float*)d_in[16];
  const float* dec_b2   = (const float*)d_in[17];
  const float* dec_w3   = (const float*)d_in[18];
  const float* dec_b3   = (const float*)d_in[19];
  float* out = (float*)d_out;

  char* ws = (char*)d_ws;
  float*  B0    = (float*)(ws);                         // 33.55 MB each
  float*  B1    = (float*)(ws + 33554432);
  float*  B2    = (float*)(ws + 67108864);
  float*  B3    = (float*)(ws + 100663296);
  float*  B4    = (float*)(ws + 134217728);             // enc1 out: 67.1 MB
  double* PART  = (double*)(ws + 201326592);
  float*  CNORM = (float*)(ws + 201326592 + 16384);
  unsigned short* CBH = (unsigned short*)(ws + 100663296);  // B3, pre-VQ only
  unsigned short* CBL = CBH + 32768;
  unsigned short* WH0 = (unsigned short*)(ws + 201359360);
  unsigned short* WL0 = WH0 + 36864;
  unsigned short* WH1 = (unsigned short*)(ws + 201359360 + 147456);
  unsigned short* WL1 = WH1 + 36864;
  unsigned short* WH2 = (unsigned short*)(ws + 201359360 + 294912);
  unsigned short* WL2 = WH2 + 36864;
  unsigned short* WH3 = (unsigned short*)(ws + 201359360 + 442368);
  unsigned short* WL3 = WH3 + 36864;
  unsigned short* WH4 = (unsigned short*)(ws + 201359360 + 589824);   // dec2
  unsigned short* WL4 = WH4 + 18432;
  unsigned short* WH5 = (unsigned short*)(ws + 201359360 + 663552);   // enc2
  unsigned short* WL5 = WH5 + 32768;
  unsigned short* WH6 = (unsigned short*)(ws + 202153984);            // res_e_w2
  unsigned short* WL6 = WH6 + 4096;
  unsigned short* WH7 = (unsigned short*)(ws + 202153984 + 16384);    // enc_w4
  unsigned short* WL7 = WH7 + 4096;
  unsigned short* WH8 = (unsigned short*)(ws + 202153984 + 32768);    // res_d_w2
  unsigned short* WL8 = WH8 + 4096;

  k_wprep<<<144, 256, 0, stream>>>(enc_w3,   WH0, WL0);
  k_wprep<<<144, 256, 0, stream>>>(res_e_w1, WH1, WL1);
  k_wprep<<<144, 256, 0, stream>>>(dec_w1,   WH2, WL2);
  k_wprep<<<144, 256, 0, stream>>>(res_d_w1, WH3, WL3);
  k_wprep2<<<72, 256, 0, stream>>>(dec_w2,   WH4, WL4);
  k_wprep_e2<<<128, 256, 0, stream>>>(enc_w2, WH5, WL5);
  k_wprep_1x1<<<16, 256, 0, stream>>>(res_e_w2, WH6, WL6);
  k_wprep_1x1<<<16, 256, 0, stream>>>(enc_w4,   WH7, WL7);
  k_wprep_1x1<<<16, 256, 0, stream>>>(res_d_w2, WH8, WL8);
  k_cbprep_m<<<128, 256, 0, stream>>>(codebook, CBH, CBL);
  k_cbnorm<<<2, 256, 0, stream>>>(codebook, CNORM);

  k_enc1m<<<1024, 256, 0, stream>>>(x_in, enc_w1, enc_b1, B4);
  k_enc2m<<<1024, 256, 0, stream>>>(B4, WH5, WL5, enc_b2, B0);
  k_conv3m<1, true ><<<512, 256, 0, stream>>>(B0, WH0, WL0, enc_b3, B1);
  k_conv3m<2, false><<<512, 256, 0, stream>>>(B1, WH1, WL1, nullptr, B2);
  k_1x1m<1, false, true ><<<2048, 256, 0, stream>>>(B2, WH6, WL6, nullptr, B1, B0);
  k_1x1m<1, true,  false><<<2048, 256, 0, stream>>>(B0, WH7, WL7, enc_b4, nullptr, B1);
  k_vq2m<<<2048, 256, 0, stream>>>(B1, CBH, CBL, codebook, CNORM, B2, PART);
  k_conv3m<1, true ><<<512, 256, 0, stream>>>(B2, WH2, WL2, dec_b1, B0);
  k_conv3m<2, false><<<512, 256, 0, stream>>>(B0, WH3, WL3, nullptr, B3);
  k_1x1m<1, false, true ><<<2048, 256, 0, stream>>>(B3, WH8, WL8, nullptr, B0, B1);
  k_dec2m<<<2048, 256, 0, stream>>>(B1, WH4, WL4, dec_b2, B4);
  k_dec3<<<1024, 256, 0, stream>>>(B4, dec_w3, dec_b3, out);
  k_loss<<<1, 256, 0, stream>>>(PART, out);
}

// Round 26
// 615.575 us; speedup vs baseline: 1.1622x; 1.1534x over previous
//
#include <hip/hip_runtime.h>

// ---------------------------------------------------------------------------
// VQ-VAE forward.  N=128.  MFMA (split-bf16 hi/lo, 3-term) for the four
// 3x3 64->64 convs, dec2 (up2x + 3x3 64->32), enc2 (4x4 s2 32->64), the
// VQ distance GEMM, and the three 1x1 channel GEMMs.  f32 VALU elsewhere.
//   x*y ~= xh*yh + xh*yl + xl*yh   (f32 MFMA accumulate)
// Activations staged in LDS as PACKED (hi | lo<<16) u32, pad 20 (proven).
// R22: dec2m interp writes vectorized.  R23: dec3 chunk-parity layout.
// R26: conv3m staging vectorized -- halo cols (always zero) written once
// before the g-loop; interior = 1280 float4 loads with shift-only indexing
// (was 5440 scalar items with /34 %34 /10 %10 magic-mul chains).  Bit-exact.
// ---------------------------------------------------------------------------

template<int ACT> __device__ __forceinline__ float actf(float x){
  if (ACT == 1) return x > 0.f ? x : 0.01f * x;   // leaky relu, slope .01
  if (ACT == 2) return fmaxf(x, 0.f);             // relu
  return x;
}

typedef __bf16 bf16x8 __attribute__((ext_vector_type(8)));
typedef float f32x16 __attribute__((ext_vector_type(16)));
typedef unsigned int u32x4v __attribute__((ext_vector_type(4)));

__device__ __forceinline__ unsigned f2bf(unsigned u){   // RTNE f32->bf16 bits
  return (u + 0x7fffu + ((u >> 16) & 1u)) >> 16;
}

// ---------------- weight prep: f32 [64co][64ci][3][3] -> hi/lo bf16 --------
__global__ __launch_bounds__(256) void k_wprep(
    const float* __restrict__ w, unsigned short* __restrict__ wh,
    unsigned short* __restrict__ wl) {
  int i = blockIdx.x * 256 + threadIdx.x;           // 36864 = 4g*9tap*2*32*16
  if (i >= 36864) return;
  int ci16 = i & 15, co = (i >> 4) & 31, cot = (i >> 9) & 1;
  int rest = i >> 10, tap = rest % 9, g = rest / 9;
  float v = w[(cot * 32 + co) * 576 + (g * 16 + ci16) * 9 + tap];
  unsigned hi = f2bf(__float_as_uint(v));
  float lf = v - __uint_as_float(hi << 16);
  unsigned lo = f2bf(__float_as_uint(lf));
  wh[i] = (unsigned short)hi;
  wl[i] = (unsigned short)lo;
}

// ---------------- weight prep for dec2: f32 [32co][64ci][3][3] -------------
__global__ __launch_bounds__(256) void k_wprep2(
    const float* __restrict__ w, unsigned short* __restrict__ wh,
    unsigned short* __restrict__ wl) {
  int i = blockIdx.x * 256 + threadIdx.x;           // 18432 = 4g*9tap*32*16
  if (i >= 18432) return;
  int ci16 = i & 15, co = (i >> 4) & 31;
  int rest = i >> 9, tap = rest % 9, g = rest / 9;
  float v = w[co * 576 + (g * 16 + ci16) * 9 + tap];
  unsigned hi = f2bf(__float_as_uint(v));
  float lf = v - __uint_as_float(hi << 16);
  unsigned lo = f2bf(__float_as_uint(lf));
  wh[i] = (unsigned short)hi;
  wl[i] = (unsigned short)lo;
}

// ---------------- weight prep for enc2: f32 [64co][32ci][4][4] -------------
__global__ __launch_bounds__(256) void k_wprep_e2(
    const float* __restrict__ w, unsigned short* __restrict__ wh,
    unsigned short* __restrict__ wl) {
  int i = blockIdx.x * 256 + threadIdx.x;           // 32768 = 2g*16tap*2*32*16
  if (i >= 32768) return;
  int ci16 = i & 15, co = (i >> 4) & 31, cot = (i >> 9) & 1;
  int rest = i >> 10, tap = rest & 15, g = rest >> 4;
  float v = w[(cot * 32 + co) * 512 + (g * 16 + ci16) * 16 + tap];
  unsigned hi = f2bf(__float_as_uint(v));
  float lf = v - __uint_as_float(hi << 16);
  unsigned lo = f2bf(__float_as_uint(lf));
  wh[i] = (unsigned short)hi;
  wl[i] = (unsigned short)lo;
}

// ---------------- codebook prep for VQ MFMA: fragment-ordered hi/lo --------
__global__ __launch_bounds__(256) void k_cbprep_m(
    const float* __restrict__ cb, unsigned short* __restrict__ ch,
    unsigned short* __restrict__ cl_) {
  int i = blockIdx.x * 256 + threadIdx.x;           // 32768 = 16ct*4s*32*16
  if (i >= 32768) return;
  int ci16 = i & 15, cc = (i >> 4) & 31, ct4s = i >> 9;
  int s = ct4s & 3, ct = ct4s >> 2;
  float v = cb[(ct * 32 + cc) * 64 + s * 16 + ci16];
  unsigned hi = f2bf(__float_as_uint(v));
  float lf = v - __uint_as_float(hi << 16);
  unsigned lo = f2bf(__float_as_uint(lf));
  ch[i] = (unsigned short)hi;
  cl_[i] = (unsigned short)lo;
}

// ---------------- weight prep for 1x1: f32 [64co][64ci] --------------------
__global__ __launch_bounds__(256) void k_wprep_1x1(
    const float* __restrict__ w, unsigned short* __restrict__ wh,
    unsigned short* __restrict__ wl) {
  int i = blockIdx.x * 256 + threadIdx.x;           // 4096 = 2ct*4s*32*16
  if (i >= 4096) return;
  int ci16 = i & 15, cc = (i >> 4) & 31, s = (i >> 9) & 3, ct = i >> 11;
  float v = w[(ct * 32 + cc) * 64 + s * 16 + ci16];
  unsigned hi = f2bf(__float_as_uint(v));
  float lf = v - __uint_as_float(hi << 16);
  unsigned lo = f2bf(__float_as_uint(lf));
  wh[i] = (unsigned short)hi;
  wl[i] = (unsigned short)lo;
}

// ---------------- codebook squared norms -----------------------------------
__global__ __launch_bounds__(256) void k_cbnorm(const float* __restrict__ cb,
                                                float* __restrict__ nrm) {
  int c = blockIdx.x * 256 + threadIdx.x;
  if (c < 512) {
    float s = 0.f;
    for (int k = 0; k < 64; ++k) { float v = cb[c * 64 + k]; s = fmaf(v, v, s); }
    nrm[c] = s;
  }
}

// ---------------- enc1: 1->32, 4x4 s2 p1, 128->64, lrelu (LDS-staged) ------
__global__ __launch_bounds__(256) void k_enc1m(
    const float* __restrict__ in, const float* __restrict__ w,
    const float* __restrict__ b, float* __restrict__ out) {
  int n = blockIdx.x >> 3, y0 = (blockIdx.x & 7) * 8;
  int t = threadIdx.x;
  __shared__ float s_in[18 * 2 * 66];   // [r][parity][col/2], cols -1..128
  __shared__ float s_w[512];
  __shared__ float s_b[32];
  const float* ip = in + n * 16384;
  for (int i = t; i < 18 * 130; i += 256) {
    int r = i / 130, c = i - r * 130;
    int iy = 2 * y0 - 1 + r, ix = c - 1;
    float v = 0.f;
    if ((unsigned)iy < 128u && (unsigned)ix < 128u) v = ip[iy * 128 + ix];
    s_in[(r * 2 + (c & 1)) * 66 + (c >> 1)] = v;
  }
  for (int i = t; i < 512; i += 256) s_w[i] = w[i];
  if (t < 32) s_b[t] = b[t];
  __syncthreads();
  int ox = t & 63, wv = t >> 6;
#pragma unroll
  for (int rr = 0; rr < 2; ++rr) {
    int oyl = wv * 2 + rr;
    float x[16];
#pragma unroll
    for (int ky = 0; ky < 4; ++ky) {
      int r = 2 * oyl + ky;
#pragma unroll
      for (int kx = 0; kx < 4; ++kx) {
        x[ky * 4 + kx] = s_in[(r * 2 + (kx & 1)) * 66 + ox + (kx >> 1)];
      }
    }
    int obase = (n * 32) * 4096 + (y0 + oyl) * 64 + ox;
    for (int co = 0; co < 32; ++co) {
      float acc = s_b[co];
      const float* wr = &s_w[co * 16];
#pragma unroll
      for (int k = 0; k < 16; ++k) acc = fmaf(x[k], wr[k], acc);
      out[obase + co * 4096] = actf<1>(acc);
    }
  }
}

// ---------------- 3x3 64->64 stride1 pad1 @32x32 via MFMA ------------------
// R26: staging vectorized.  Halo cols c=0/c=33 (col=-1/32, always OOB->0)
// written ONCE before the g loop (interior never touches them).  Interior:
// 1280 float4 loads, i = cq + 8*ci + 128*r (all shifts), lanes cq-fastest
// -> 128B-contiguous global segments.  Same values, same destinations.
template<int ACT, bool BIAS>
__global__ __launch_bounds__(256, 3) void k_conv3m(
    const float* __restrict__ in, const unsigned short* __restrict__ wh,
    const unsigned short* __restrict__ wl, const float* __restrict__ bias,
    float* __restrict__ out) {
  int n = blockIdx.x >> 2, y0 = (blockIdx.x & 3) * 8;
  int t = threadIdx.x;
  int lane = t & 63, wv = t >> 6;
  int cot = wv & 1, rgroup = wv >> 1;
  int cc = lane & 31, h = lane >> 5;

  __shared__ __align__(16) unsigned int s_x[6800];   // [10 r][34 c][pad 20 ci]

  const uint4* wh4 = reinterpret_cast<const uint4*>(wh);
  const uint4* wl4 = reinterpret_cast<const uint4*>(wl);

  f32x16 acc[4];
#pragma unroll
  for (int r = 0; r < 4; ++r)
#pragma unroll
    for (int j = 0; j < 16; ++j) acc[r][j] = 0.f;

  // halo columns are always zero (col=-1 and col=32 are out of bounds);
  // write once -- interior staging never overwrites c=0 or c=33.
  for (int i = t; i < 320; i += 256) {
    int ci = i & 15, rh = i >> 4;          // rh 0..19
    int r = rh >> 1, c = (rh & 1) ? 33 : 0;
    s_x[(r * 34 + c) * 20 + ci] = 0u;
  }

  for (int g = 0; g < 4; ++g) {
    if (g) __syncthreads();
#pragma unroll
    for (int k = 0; k < 5; ++k) {
      int i = t + (k << 8);                       // 0..1279
      int cq = i & 7, ci = (i >> 3) & 15, r = i >> 7;   // r 0..9
      int row = y0 - 1 + r;
      float4 v4 = make_float4(0.f, 0.f, 0.f, 0.f);
      if ((unsigned)row < 32u)
        v4 = *reinterpret_cast<const float4*>(
            &in[(n * 64 + g * 16 + ci) * 1024 + row * 32 + cq * 4]);
      float vv[4] = {v4.x, v4.y, v4.z, v4.w};
#pragma unroll
      for (int j = 0; j < 4; ++j) {
        unsigned hi = f2bf(__float_as_uint(vv[j]));
        float lf = vv[j] - __uint_as_float(hi << 16);
        unsigned lo = f2bf(__float_as_uint(lf));
        s_x[(r * 34 + 1 + cq * 4 + j) * 20 + ci] = hi | (lo << 16);
      }
    }
    __syncthreads();

#pragma unroll
    for (int kx = 0; kx < 3; ++kx) {
      bf16x8 Ah[3], Al[3];
#pragma unroll
      for (int ky = 0; ky < 3; ++ky) {
        int wi = ((g * 9 + ky * 3 + kx) * 2 + cot) * 64 + cc * 2 + h;
        Ah[ky] = __builtin_bit_cast(bf16x8, wh4[wi]);
        Al[ky] = __builtin_bit_cast(bf16x8, wl4[wi]);
      }
#pragma unroll
      for (int ir6 = 0; ir6 < 6; ++ir6) {
        int ir = rgroup * 4 + ir6;
        const uint4* xp = reinterpret_cast<const uint4*>(
            &s_x[(ir * 34 + cc + kx) * 20 + (h << 3)]);
        uint4 qa = xp[0], qb = xp[1];
        u32x4v bh, bl;
        bh[0] = (qa.x & 0xffffu) | (qa.y << 16);
        bh[1] = (qa.z & 0xffffu) | (qa.w << 16);
        bh[2] = (qb.x & 0xffffu) | (qb.y << 16);
        bh[3] = (qb.z & 0xffffu) | (qb.w << 16);
        bl[0] = (qa.x >> 16) | (qa.y & 0xffff0000u);
        bl[1] = (qa.z >> 16) | (qa.w & 0xffff0000u);
        bl[2] = (qb.x >> 16) | (qb.y & 0xffff0000u);
        bl[3] = (qb.z >> 16) | (qb.w & 0xffff0000u);
        bf16x8 Bh = __builtin_bit_cast(bf16x8, bh);
        bf16x8 Bl = __builtin_bit_cast(bf16x8, bl);
#pragma unroll
        for (int ky = 0; ky < 3; ++ky) {
          int rr = ir6 - ky;
          if (rr < 0 || rr > 3) continue;
          acc[rr] = __builtin_amdgcn_mfma_f32_32x32x16_bf16(Ah[ky], Bh, acc[rr], 0, 0, 0);
          acc[rr] = __builtin_amdgcn_mfma_f32_32x32x16_bf16(Ah[ky], Bl, acc[rr], 0, 0, 0);
          acc[rr] = __builtin_amdgcn_mfma_f32_32x32x16_bf16(Al[ky], Bh, acc[rr], 0, 0, 0);
        }
      }
    }
  }

  float bvv[16];
#pragma unroll
  for (int reg = 0; reg < 16; ++reg) {
    int row = (reg & 3) + 8 * (reg >> 2) + 4 * h;
    bvv[reg] = BIAS ? bias[cot * 32 + row] : 0.f;
  }
#pragma unroll
  for (int rr = 0; rr < 4; ++rr) {
    int y = y0 + rgroup * 4 + rr;
#pragma unroll
    for (int reg = 0; reg < 16; ++reg) {
      int row = (reg & 3) + 8 * (reg >> 2) + 4 * h;
      int co = cot * 32 + row;
      float v = acc[rr][reg] + bvv[reg];
      out[(n * 64 + co) * 1024 + y * 32 + cc] = actf<ACT>(v);
    }
  }
}

// ---------------- enc2: 32->64, 4x4 s2 p1, 64->32 via MFMA -----------------
__global__ __launch_bounds__(256, 2) void k_enc2m(
    const float* __restrict__ in, const unsigned short* __restrict__ wh,
    const unsigned short* __restrict__ wl, const float* __restrict__ bias,
    float* __restrict__ out) {
  int n = blockIdx.x >> 3, y0 = (blockIdx.x & 7) * 4;
  int t = threadIdx.x;
  int lane = t & 63, wv = t >> 6;
  int cot = wv & 1, rg = wv >> 1;
  int cc = lane & 31, h = lane >> 5;

  __shared__ __align__(16) unsigned int s_x[13200];  // [10][2][33][20]

  const uint4* wh4 = reinterpret_cast<const uint4*>(wh);
  const uint4* wl4 = reinterpret_cast<const uint4*>(wl);

  f32x16 acc[2];
#pragma unroll
  for (int r = 0; r < 2; ++r)
#pragma unroll
    for (int j = 0; j < 16; ++j) acc[r][j] = 0.f;

  for (int g = 0; g < 2; ++g) {
    if (g) __syncthreads();
    for (int i = t; i < 10560; i += 256) {
      int ci = i / 660, rem = i - ci * 660;
      int r = rem / 66, c = rem - r * 66;
      int row = 2 * y0 - 1 + r, icol = c - 1;
      float v = 0.f;
      if ((unsigned)row < 64u && (unsigned)icol < 64u)
        v = in[((n * 32 + g * 16 + ci) * 64 + row) * 64 + icol];
      unsigned hi = f2bf(__float_as_uint(v));
      float lf = v - __uint_as_float(hi << 16);
      unsigned lo = f2bf(__float_as_uint(lf));
      int p = icol & 1;
      int idx = (icol + p) >> 1;
      s_x[((r * 2 + p) * 33 + idx) * 20 + ci] = hi | (lo << 16);
    }
    __syncthreads();

#pragma unroll
    for (int kx = 0; kx < 4; ++kx) {
      bf16x8 Ah[4], Al[4];
#pragma unroll
      for (int ky = 0; ky < 4; ++ky) {
        int wi = ((g * 16 + ky * 4 + kx) * 2 + cot) * 64 + cc * 2 + h;
        Ah[ky] = __builtin_bit_cast(bf16x8, wh4[wi]);
        Al[ky] = __builtin_bit_cast(bf16x8, wl4[wi]);
      }
      int p = (kx + 1) & 1;
      int idx = cc + (kx >> 1);
#pragma unroll
      for (int ir6 = 0; ir6 < 6; ++ir6) {
        int r = rg * 4 + ir6;
        const uint4* xp = reinterpret_cast<const uint4*>(
            &s_x[((r * 2 + p) * 33 + idx) * 20 + (h << 3)]);
        uint4 qa = xp[0], qb = xp[1];
        u32x4v bh, bl;
        bh[0] = (qa.x & 0xffffu) | (qa.y << 16);
        bh[1] = (qa.z & 0xffffu) | (qa.w << 16);
        bh[2] = (qb.x & 0xffffu) | (qb.y << 16);
        bh[3] = (qb.z & 0xffffu) | (qb.w << 16);
        bl[0] = (qa.x >> 16) | (qa.y & 0xffff0000u);
        bl[1] = (qa.z >> 16) | (qa.w & 0xffff0000u);
        bl[2] = (qb.x >> 16) | (qb.y & 0xffff0000u);
        bl[3] = (qb.z >> 16) | (qb.w & 0xffff0000u);
        bf16x8 Bh = __builtin_bit_cast(bf16x8, bh);
        bf16x8 Bl = __builtin_bit_cast(bf16x8, bl);
#pragma unroll
        for (int rr = 0; rr < 2; ++rr) {
          int ky = ir6 - 2 * rr;
          if (ky < 0 || ky > 3) continue;
          acc[rr] = __builtin_amdgcn_mfma_f32_32x32x16_bf16(Ah[ky], Bh, acc[rr], 0, 0, 0);
          acc[rr] = __builtin_amdgcn_mfma_f32_32x32x16_bf16(Ah[ky], Bl, acc[rr], 0, 0, 0);
          acc[rr] = __builtin_amdgcn_mfma_f32_32x32x16_bf16(Al[ky], Bh, acc[rr], 0, 0, 0);
        }
      }
    }
  }

#pragma unroll
  for (int rr = 0; rr < 2; ++rr) {
    int oy = y0 + rg * 2 + rr;
#pragma unroll
    for (int reg = 0; reg < 16; ++reg) {
      int corow = (reg & 3) + 8 * (reg >> 2) + 4 * h;
      int co = cot * 32 + corow;
      float v = acc[rr][reg] + bias[co];
      out[(n * 64 + co) * 1024 + oy * 32 + cc] = actf<1>(v);
    }
  }
}

// ---------------- 1x1 64->64 via MFMA (vq2m-machinery subset) --------------
template<int ACT, bool BIAS, bool ADD>
__global__ __launch_bounds__(256, 2) void k_1x1m(
    const float* __restrict__ in, const unsigned short* __restrict__ wh,
    const unsigned short* __restrict__ wl, const float* __restrict__ bias,
    const float* __restrict__ add, float* __restrict__ out) {
  int bid = blockIdx.x;                  // 2048 = 128 n x 16 s-tiles
  int n = bid >> 4, s0 = (bid & 15) << 6;
  int t = threadIdx.x;
  int lane = t & 63, wv = t >> 6;
  int cc = lane & 31, h = lane >> 5;
  int ct = wv & 1, pt = wv >> 1;

  __shared__ __align__(16) unsigned int s_pk[5120];   // [4 s][64 pos][pad 20]

  for (int i = t; i < 4096; i += 256) {
    int pos = i & 63, k = i >> 6;
    float v = in[(n * 64 + k) * 1024 + s0 + pos];
    unsigned hi = f2bf(__float_as_uint(v));
    float lf = v - __uint_as_float(hi << 16);
    unsigned lo = f2bf(__float_as_uint(lf));
    s_pk[(((k >> 4) * 64) + pos) * 20 + (k & 15)] = hi | (lo << 16);
  }
  __syncthreads();

  const uint4* ah4 = reinterpret_cast<const uint4*>(wh);
  const uint4* al4 = reinterpret_cast<const uint4*>(wl);

  f32x16 acc;
#pragma unroll
  for (int j = 0; j < 16; ++j) acc[j] = 0.f;

#pragma unroll
  for (int s = 0; s < 4; ++s) {
    const uint4* xp = reinterpret_cast<const uint4*>(
        &s_pk[((s * 64) + pt * 32 + cc) * 20 + (h << 3)]);
    uint4 qa = xp[0], qb = xp[1];
    u32x4v bh, bl;
    bh[0] = (qa.x & 0xffffu) | (qa.y << 16);
    bh[1] = (qa.z & 0xffffu) | (qa.w << 16);
    bh[2] = (qb.x & 0xffffu) | (qb.y << 16);
    bh[3] = (qb.z & 0xffffu) | (qb.w << 16);
    bl[0] = (qa.x >> 16) | (qa.y & 0xffff0000u);
    bl[1] = (qa.z >> 16) | (qa.w & 0xffff0000u);
    bl[2] = (qb.x >> 16) | (qb.y & 0xffff0000u);
    bl[3] = (qb.z >> 16) | (qb.w & 0xffff0000u);
    bf16x8 Bh = __builtin_bit_cast(bf16x8, bh);
    bf16x8 Bl = __builtin_bit_cast(bf16x8, bl);
    int wi = (ct * 4 + s) * 64 + cc * 2 + h;
    bf16x8 Ah = __builtin_bit_cast(bf16x8, ah4[wi]);
    bf16x8 Al = __builtin_bit_cast(bf16x8, al4[wi]);
    acc = __builtin_amdgcn_mfma_f32_32x32x16_bf16(Ah, Bh, acc, 0, 0, 0);
    acc = __builtin_amdgcn_mfma_f32_32x32x16_bf16(Ah, Bl, acc, 0, 0, 0);
    acc = __builtin_amdgcn_mfma_f32_32x32x16_bf16(Al, Bh, acc, 0, 0, 0);
  }

  int pos = pt * 32 + cc;
#pragma unroll
  for (int reg = 0; reg < 16; ++reg) {
    int row = (reg & 3) + 8 * (reg >> 2) + 4 * h;
    int co = ct * 32 + row;
    float v = acc[reg] + (BIAS ? bias[co] : 0.f);
    int gi = (n * 64 + co) * 1024 + s0 + pos;
    if (ADD) v += add[gi];
    out[gi] = actf<ACT>(v);
  }
}

// ---------------- VQ via MFMA: dist GEMM + argmin + q + loss ---------------
__global__ __launch_bounds__(256, 2) void k_vq2m(
    const float* __restrict__ lat, const unsigned short* __restrict__ cbh,
    const unsigned short* __restrict__ cbl, const float* __restrict__ cb,
    const float* __restrict__ nrm, float* __restrict__ q,
    double* __restrict__ part) {
  int bid = blockIdx.x;                  // 2048 = 128 n x 16 s-tiles
  int n = bid >> 4, s0 = (bid & 15) << 6;
  int t = threadIdx.x;
  int lane = t & 63, wv = t >> 6;
  int cc = lane & 31, h = lane >> 5;

  __shared__ __align__(16) unsigned int s_pk[5120];   // [4 s][64 pos][pad 20]
  __shared__ float s_lat_f[4096];                     // [k][pos]
  __shared__ float s_nrm[512];
  __shared__ float s_rd[512];                         // [pos][8 slots]
  __shared__ int   s_ri[512];
  __shared__ int   s_sel[64];
  __shared__ double s_r[256];

  for (int i = t; i < 4096; i += 256) {
    int pos = i & 63, k = i >> 6;
    float v = lat[(n * 64 + k) * 1024 + s0 + pos];
    s_lat_f[k * 64 + pos] = v;
    unsigned hi = f2bf(__float_as_uint(v));
    float lf = v - __uint_as_float(hi << 16);
    unsigned lo = f2bf(__float_as_uint(lf));
    s_pk[(((k >> 4) * 64) + pos) * 20 + (k & 15)] = hi | (lo << 16);
  }
  for (int i = t; i < 512; i += 256) s_nrm[i] = nrm[i];
  __syncthreads();

  const uint4* ah4 = reinterpret_cast<const uint4*>(cbh);
  const uint4* al4 = reinterpret_cast<const uint4*>(cbl);

  float best[2] = {3.4e38f, 3.4e38f};
  int bidx[2] = {0, 0};

#pragma unroll
  for (int ip = 0; ip < 2; ++ip) {
    f32x16 acc[2][2];
#pragma unroll
    for (int a = 0; a < 2; ++a)
#pragma unroll
      for (int b = 0; b < 2; ++b)
#pragma unroll
        for (int j = 0; j < 16; ++j) acc[a][b][j] = 0.f;

#pragma unroll
    for (int s = 0; s < 4; ++s) {
      bf16x8 Bh[2], Bl[2];
#pragma unroll
      for (int pt = 0; pt < 2; ++pt) {
        const uint4* xp = reinterpret_cast<const uint4*>(
            &s_pk[((s * 64) + pt * 32 + cc) * 20 + (h << 3)]);
        uint4 qa = xp[0], qb = xp[1];
        u32x4v bh, bl;
        bh[0] = (qa.x & 0xffffu) | (qa.y << 16);
        bh[1] = (qa.z & 0xffffu) | (qa.w << 16);
        bh[2] = (qb.x & 0xffffu) | (qb.y << 16);
        bh[3] = (qb.z & 0xffffu) | (qb.w << 16);
        bl[0] = (qa.x >> 16) | (qa.y & 0xffff0000u);
        bl[1] = (qa.z >> 16) | (qa.w & 0xffff0000u);
        bl[2] = (qb.x >> 16) | (qb.y & 0xffff0000u);
        bl[3] = (qb.z >> 16) | (qb.w & 0xffff0000u);
        Bh[pt] = __builtin_bit_cast(bf16x8, bh);
        Bl[pt] = __builtin_bit_cast(bf16x8, bl);
      }
#pragma unroll
      for (int it2 = 0; it2 < 2; ++it2) {
        int ct = wv * 4 + ip * 2 + it2;
        int wi = (ct * 4 + s) * 64 + cc * 2 + h;
        bf16x8 Ah = __builtin_bit_cast(bf16x8, ah4[wi]);
        bf16x8 Al = __builtin_bit_cast(bf16x8, al4[wi]);
#pragma unroll
        for (int pt = 0; pt < 2; ++pt) {
          acc[it2][pt] = __builtin_amdgcn_mfma_f32_32x32x16_bf16(Ah, Bh[pt], acc[it2][pt], 0, 0, 0);
          acc[it2][pt] = __builtin_amdgcn_mfma_f32_32x32x16_bf16(Ah, Bl[pt], acc[it2][pt], 0, 0, 0);
          acc[it2][pt] = __builtin_amdgcn_mfma_f32_32x32x16_bf16(Al, Bh[pt], acc[it2][pt], 0, 0, 0);
        }
      }
    }

#pragma unroll
    for (int it2 = 0; it2 < 2; ++it2) {
      int ct = wv * 4 + ip * 2 + it2;
#pragma unroll
      for (int pt = 0; pt < 2; ++pt) {
#pragma unroll
        for (int reg = 0; reg < 16; ++reg) {
          int code = ct * 32 + (reg & 3) + 8 * (reg >> 2) + 4 * h;
          float d = fmaf(-2.f, acc[it2][pt][reg], s_nrm[code]);
          if (d < best[pt] || (d == best[pt] && code < bidx[pt])) {
            best[pt] = d; bidx[pt] = code;
          }
        }
      }
    }
  }

#pragma unroll
  for (int pt = 0; pt < 2; ++pt) {
    int pos = pt * 32 + cc;
    s_rd[pos * 8 + wv * 2 + h] = best[pt];
    s_ri[pos * 8 + wv * 2 + h] = bidx[pt];
  }
  __syncthreads();
  if (t < 64) {
    float bd = s_rd[t * 8]; int bi = s_ri[t * 8];
#pragma unroll
    for (int m = 1; m < 8; ++m) {
      float d = s_rd[t * 8 + m]; int ii = s_ri[t * 8 + m];
      if (d < bd || (d == bd && ii < bi)) { bd = d; bi = ii; }
    }
    s_sel[t] = bi;
  }
  __syncthreads();

  int pos = t & 63, dg = t >> 6;
  int bsel = s_sel[pos];
  const float* cw = cb + bsel * 64 + dg * 16;
  float psum = 0.f;
#pragma unroll
  for (int kk = 0; kk < 16; ++kk) {
    int k = dg * 16 + kk;
    float cv = cw[kk];
    float l = s_lat_f[k * 64 + pos];
    float df = cv - l;
    psum = fmaf(df, df, psum);
    q[(n * 64 + k) * 1024 + s0 + pos] = cv;
  }
  s_r[t] = (double)psum;
  __syncthreads();
  for (int str = 128; str > 0; str >>= 1) {
    if (t < str) s_r[t] += s_r[t + str];
    __syncthreads();
  }
  if (t == 0) part[bid] = s_r[0];
}

// ---------------- dec2: up2x(ac) + 3x3 64->32 + lrelu, via MFMA ------------
// R22: interp packs into registers (static-indexed, fully unrolled), then
// 4+4 ds_write_b128 per thread per g (was 32 scalar ds_write_b32).
__global__ __launch_bounds__(256, 3) void k_dec2m(
    const float* __restrict__ in, const unsigned short* __restrict__ wh,
    const unsigned short* __restrict__ wl, const float* __restrict__ bias,
    float* __restrict__ out) {
  int n = blockIdx.x >> 4, y0 = (blockIdx.x & 15) * 4;
  int t = threadIdx.x;
  int lane = t & 63, wv = t >> 6;
  int xh = wv & 1, rg = wv >> 1;
  int cc = lane & 31, h = lane >> 5;

  __shared__ __align__(16) unsigned int s_x[6 * 66 * 20];   // packed up-tile
  __shared__ float s_src[16 * 165];                         // [ci][5r][33]
  __shared__ float2 s_wmy[6];
  __shared__ int2   s_ryp[6];
  __shared__ float2 s_wmx[66];
  __shared__ int2   s_rxp[66];

  const float sc = 31.0f / 63.0f;
  int r0 = (y0 == 0) ? 0 : (int)floorf((float)(y0 - 1) * sc);

  if (t < 6) {
    int uy = y0 - 1 + t;
    int uyc = min(max(uy, 0), 63);
    float sy = (float)uyc * sc;
    int iy0 = (int)floorf(sy);
    s_wmy[t] = make_float2(sy - (float)iy0, ((unsigned)uy < 64u) ? 1.f : 0.f);
    s_ryp[t] = make_int2(iy0 - r0, min(iy0 + 1, 31) - r0);
  }
  int xc = t - 64;
  if (xc >= 0 && xc < 66) {
    int ux = xc - 1;
    int uxc = min(max(ux, 0), 63);
    float sx = (float)uxc * sc;
    int ix0 = (int)floorf(sx);
    s_wmx[xc] = make_float2(sx - (float)ix0, ((unsigned)ux < 64u) ? 1.f : 0.f);
    s_rxp[xc] = make_int2(ix0, min(ix0 + 1, 31));
  }

  // stage g=0 src: 16 ci x 5 rows x 32 cols
  for (int i = t; i < 2560; i += 256) {
    int ci = i / 160, rem = i - ci * 160;
    int rr = rem >> 5, c = rem & 31;
    int row = r0 + rr;
    s_src[ci * 165 + rr * 33 + c] =
        (row < 32) ? in[(n * 64 + ci) * 1024 + row * 32 + c] : 0.f;
  }
  __syncthreads();

  // slot setup: slot 0 (pos = t) always valid; slot 1 (pos = t+256) for t<140
  int so00[2], so01[2], so10[2], so11[2], spos[2];
  float swy[2], swx[2], smm[2];
  bool sval1;
  {
    int p = t;
    int u = p / 66, c = p - u * 66;
    float2 wmy = s_wmy[u]; int2 ry = s_ryp[u];
    float2 wmx = s_wmx[c]; int2 rx = s_rxp[c];
    swy[0] = wmy.x; swx[0] = wmx.x; smm[0] = wmy.y * wmx.y;
    so00[0] = ry.x * 33 + rx.x; so01[0] = ry.x * 33 + rx.y;
    so10[0] = ry.y * 33 + rx.x; so11[0] = ry.y * 33 + rx.y;
    spos[0] = p * 20;
  }
  {
    int pos1 = t + 256;
    sval1 = pos1 < 396;
    int p = sval1 ? pos1 : 0;
    int u = p / 66, c = p - u * 66;
    float2 wmy = s_wmy[u]; int2 ry = s_ryp[u];
    float2 wmx = s_wmx[c]; int2 rx = s_rxp[c];
    swy[1] = wmy.x; swx[1] = wmx.x; smm[1] = wmy.y * wmx.y;
    so00[1] = ry.x * 33 + rx.x; so01[1] = ry.x * 33 + rx.y;
    so10[1] = ry.y * 33 + rx.x; so11[1] = ry.y * 33 + rx.y;
    spos[1] = p * 20;
  }

  const uint4* wh4 = reinterpret_cast<const uint4*>(wh);
  const uint4* wl4 = reinterpret_cast<const uint4*>(wl);

  f32x16 acc[2];
#pragma unroll
  for (int r = 0; r < 2; ++r)
#pragma unroll
    for (int j = 0; j < 16; ++j) acc[r][j] = 0.f;

  for (int g = 0; g < 4; ++g) {
    // ---- interp + split-pack into registers (static indices) ----
    unsigned pk0[16], pk1[16];
#pragma unroll
    for (int ci = 0; ci < 16; ++ci) {
      const float* sp = s_src + ci * 165;
      {
        float a00 = sp[so00[0]], a01 = sp[so01[0]];
        float a10 = sp[so10[0]], a11 = sp[so11[0]];
        float h0 = fmaf(a10 - a00, swy[0], a00);
        float h1 = fmaf(a11 - a01, swy[0], a01);
        float v = smm[0] * fmaf(h1 - h0, swx[0], h0);
        __bf16 hb = (__bf16)v;
        float hf = (float)hb;
        __bf16 lb = (__bf16)(v - hf);
        pk0[ci] = (unsigned)__builtin_bit_cast(unsigned short, hb)
                | ((unsigned)__builtin_bit_cast(unsigned short, lb) << 16);
      }
      {
        float a00 = sp[so00[1]], a01 = sp[so01[1]];
        float a10 = sp[so10[1]], a11 = sp[so11[1]];
        float h0 = fmaf(a10 - a00, swy[1], a00);
        float h1 = fmaf(a11 - a01, swy[1], a01);
        float v = smm[1] * fmaf(h1 - h0, swx[1], h0);
        __bf16 hb = (__bf16)v;
        float hf = (float)hb;
        __bf16 lb = (__bf16)(v - hf);
        pk1[ci] = (unsigned)__builtin_bit_cast(unsigned short, hb)
                | ((unsigned)__builtin_bit_cast(unsigned short, lb) << 16);
      }
    }
    // ---- vectorized LDS writes: 4 (+4) x ds_write_b128 ----
#pragma unroll
    for (int qd = 0; qd < 4; ++qd) {
      *reinterpret_cast<uint4*>(&s_x[spos[0] + qd * 4]) =
          make_uint4(pk0[qd * 4], pk0[qd * 4 + 1], pk0[qd * 4 + 2], pk0[qd * 4 + 3]);
    }
    if (sval1) {
#pragma unroll
      for (int qd = 0; qd < 4; ++qd) {
        *reinterpret_cast<uint4*>(&s_x[spos[1] + qd * 4]) =
            make_uint4(pk1[qd * 4], pk1[qd * 4 + 1], pk1[qd * 4 + 2], pk1[qd * 4 + 3]);
      }
    }
    __syncthreads();

    // ---- stage next src group (overlaps MFMA) ----
    if (g < 3) {
      int ci0 = (g + 1) * 16;
      for (int i = t; i < 2560; i += 256) {
        int ci = i / 160, rem = i - ci * 160;
        int rr = rem >> 5, c = rem & 31;
        int row = r0 + rr;
        s_src[ci * 165 + rr * 33 + c] =
            (row < 32) ? in[(n * 64 + ci0 + ci) * 1024 + row * 32 + c] : 0.f;
      }
    }

    // ---- MFMA ----
#pragma unroll
    for (int kx = 0; kx < 3; ++kx) {
      bf16x8 Ah[3], Al[3];
#pragma unroll
      for (int ky = 0; ky < 3; ++ky) {
        int wi = (g * 9 + ky * 3 + kx) * 64 + cc * 2 + h;
        Ah[ky] = __builtin_bit_cast(bf16x8, wh4[wi]);
        Al[ky] = __builtin_bit_cast(bf16x8, wl4[wi]);
      }
#pragma unroll
      for (int u6 = 0; u6 < 4; ++u6) {
        int u = rg * 2 + u6;
        const uint4* xp = reinterpret_cast<const uint4*>(
            &s_x[(u * 66 + xh * 32 + cc + kx) * 20 + (h << 3)]);
        uint4 qa = xp[0], qb = xp[1];
        u32x4v bh, bl;
        bh[0] = (qa.x & 0xffffu) | (qa.y << 16);
        bh[1] = (qa.z & 0xffffu) | (qa.w << 16);
        bh[2] = (qb.x & 0xffffu) | (qb.y << 16);
        bh[3] = (qb.z & 0xffffu) | (qb.w << 16);
        bl[0] = (qa.x >> 16) | (qa.y & 0xffff0000u);
        bl[1] = (qa.z >> 16) | (qa.w & 0xffff0000u);
        bl[2] = (qb.x >> 16) | (qb.y & 0xffff0000u);
        bl[3] = (qb.z >> 16) | (qb.w & 0xffff0000u);
        bf16x8 Bh = __builtin_bit_cast(bf16x8, bh);
        bf16x8 Bl = __builtin_bit_cast(bf16x8, bl);
#pragma unroll
        for (int ky = 0; ky < 3; ++ky) {
          int rr = u6 - ky;
          if (rr < 0 || rr > 1) continue;
          acc[rr] = __builtin_amdgcn_mfma_f32_32x32x16_bf16(Ah[ky], Bh, acc[rr], 0, 0, 0);
          acc[rr] = __builtin_amdgcn_mfma_f32_32x32x16_bf16(Ah[ky], Bl, acc[rr], 0, 0, 0);
          acc[rr] = __builtin_amdgcn_mfma_f32_32x32x16_bf16(Al[ky], Bh, acc[rr], 0, 0, 0);
        }
      }
    }
    __syncthreads();
  }

  float bvv[16];
#pragma unroll
  for (int reg = 0; reg < 16; ++reg) {
    int co = (reg & 3) + 8 * (reg >> 2) + 4 * h;
    bvv[reg] = bias[co];
  }
#pragma unroll
  for (int rr = 0; rr < 2; ++rr) {
    int y = y0 + rg * 2 + rr;
#pragma unroll
    for (int reg = 0; reg < 16; ++reg) {
      int co = (reg & 3) + 8 * (reg >> 2) + 4 * h;
      float v = acc[rr][reg] + bvv[reg];
      out[(n * 32 + co) * 4096 + y * 64 + xh * 32 + cc] = actf<1>(v);
    }
  }
}

// ---------------- loss finalize --------------------------------------------
__global__ __launch_bounds__(256) void k_loss(const double* __restrict__ part,
                                              float* __restrict__ out) {
  __shared__ double s[256];
  int t = threadIdx.x;
  double acc = 0.0;
  for (int i = t; i < 2048; i += 256) acc += part[i];
  s[t] = acc;
  __syncthreads();
  for (int str = 128; str > 0; str >>= 1) {
    if (t < str) s[t] += s[t + str];
    __syncthreads();
  }
  if (t == 0) {
    double mean = s[0] / 8388608.0;
    out[2097152] = (float)mean;
    out[2097153] = (float)(0.25 * mean);
  }
}

// ---------------- dec3: up2x(ac) + 3x3 32->1 + relu ------------------------
// FULL-WIDTH tiles: block = (n, 16-row strip), all 128 cols.
// R23 chunk-parity layout; min-waves 4 (R24's 5 regressed: grid-limited).
__global__ __launch_bounds__(256, 4) void k_dec3(
    const float* __restrict__ in, const float* __restrict__ w,
    const float* __restrict__ bias, float* __restrict__ out) {
  int bid = blockIdx.x;                  // 1024 = 128n * 8yT
  int n = bid >> 3, yT = bid & 7;
  int y0 = yT * 16;
  int t = threadIdx.x;
  int ty = t >> 4, xq = t & 15;          // 16 rows x 16 colgroups of 8

  __shared__ __align__(16) float s_up[2 * 18 * 136];  // [ci][18 u][34 chunks]
  __shared__ float s_src[2 * 11 * 66];   // [ci][11 r][64 c pad 66]
  __shared__ float s_w[288];
  __shared__ float2 s_wmy[18];
  __shared__ int2   s_ryp[18];
  __shared__ float2 s_wmx[130];
  __shared__ int2   s_rxp[130];

  const float sc = 63.0f / 127.0f;
  int r0 = (y0 == 0) ? 0 : (int)floorf((float)(y0 - 1) * sc);

  if (t < 18) {
    int uy = y0 - 1 + t;
    int uyc = min(max(uy, 0), 127);
    float sy = (float)uyc * sc;
    int iy0 = (int)floorf(sy);
    s_wmy[t] = make_float2(sy - (float)iy0, ((unsigned)uy < 128u) ? 1.f : 0.f);
    s_ryp[t] = make_int2(iy0 - r0, min(iy0 + 1, 63) - r0);
  }
  if (t < 130) {
    int ux = t - 1;
    int uxc = min(max(ux, 0), 127);
    float sx = (float)uxc * sc;
    int ix0 = (int)floorf(sx);
    s_wmx[t] = make_float2(sx - (float)ix0, ((unsigned)ux < 128u) ? 1.f : 0.f);
    s_rxp[t] = make_int2(ix0, min(ix0 + 1, 63));
  }
  for (int i = t; i < 288; i += 256) s_w[i] = w[i];

  float acc[8];
#pragma unroll
  for (int xx = 0; xx < 8; ++xx) acc[xx] = 0.f;

  // prologue stage g=0 (2 ci): aligned full-width rows
  for (int i = t; i < 2 * 11 * 64; i += 256) {
    int ci = i / 704, rem = i - ci * 704;
    int rr = rem >> 6, c = rem & 63;
    int row = r0 + rr;
    s_src[(ci * 11 + rr) * 66 + c] =
        (row < 64) ? in[((n * 32 + ci) * 64 + row) * 64 + c] : 0.f;
  }
  __syncthreads();

  for (int g = 0; g < 16; ++g) {
#pragma unroll
    for (int ci = 0; ci < 2; ++ci) {
      const float* sp = s_src + ci * 726;
      float* up = s_up + ci * 2448;      // 18 * 136
      for (int i = t; i < 2304; i += 256) {
        int u = i >> 7, c = i & 127;
        float2 wmy = s_wmy[u]; int2 ry = s_ryp[u];
        float2 wmx = s_wmx[c]; int2 rx = s_rxp[c];
        const float* r0p = sp + ry.x * 66;
        const float* r1p = sp + ry.y * 66;
        float a00 = r0p[rx.x], a01 = r0p[rx.y];
        float a10 = r1p[rx.x], a11 = r1p[rx.y];
        float h0 = fmaf(a10 - a00, wmy.x, a00);
        float h1 = fmaf(a11 - a01, wmy.x, a01);
        // chunk-parity position: k = c>>2; even -> k/2, odd -> 17 + k/2
        int cp = ((c & 4) ? (68 + ((c >> 3) << 2)) : ((c >> 3) << 2)) + (c & 3);
        up[u * 136 + cp] = (wmy.y * wmx.y) * fmaf(h1 - h0, wmx.x, h0);
      }
      if (t < 36) {
        int u = t >> 1, c = 128 + (t & 1);
        float2 wmy = s_wmy[u]; int2 ry = s_ryp[u];
        float2 wmx = s_wmx[c]; int2 rx = s_rxp[c];
        const float* r0p = sp + ry.x * 66;
        const float* r1p = sp + ry.y * 66;
        float a00 = r0p[rx.x], a01 = r0p[rx.y];
        float a10 = r1p[rx.x], a11 = r1p[rx.y];
        float h0 = fmaf(a10 - a00, wmy.x, a00);
        float h1 = fmaf(a11 - a01, wmy.x, a01);
        int cp = ((c & 4) ? (68 + ((c >> 3) << 2)) : ((c >> 3) << 2)) + (c & 3);
        up[u * 136 + cp] = (wmy.y * wmx.y) * fmaf(h1 - h0, wmx.x, h0);
      }
    }
    __syncthreads();

    if (g < 15) {
      int ci0 = (g + 1) * 2;
      for (int i = t; i < 2 * 11 * 64; i += 256) {
        int ci = i / 704, rem = i - ci * 704;
        int rr = rem >> 6, c = rem & 63;
        int row = r0 + rr;
        s_src[(ci * 11 + rr) * 66 + c] =
            (row < 64) ? in[((n * 32 + ci0 + ci) * 64 + row) * 64 + c] : 0.f;
      }
    }

    int ci0 = g * 2;
#pragma unroll
    for (int ci = 0; ci < 2; ++ci) {
#pragma unroll
      for (int ky = 0; ky < 3; ++ky) {
        int rbase = (ci * 18 + ty + ky) * 136;
        // chunks 2xq, 2xq+1, 2xq+2 -> float positions 4xq, 68+4xq, 4xq+4
        float4 q0 = *reinterpret_cast<const float4*>(&s_up[rbase + xq * 4]);
        float4 q1 = *reinterpret_cast<const float4*>(&s_up[rbase + 68 + xq * 4]);
        float4 q2 = *reinterpret_cast<const float4*>(&s_up[rbase + xq * 4 + 4]);
        float rv[12] = {q0.x, q0.y, q0.z, q0.w, q1.x, q1.y, q1.z, q1.w,
                        q2.x, q2.y, q2.z, q2.w};
#pragma unroll
        for (int kx = 0; kx < 3; ++kx) {
          float wv = s_w[(ci0 + ci) * 9 + ky * 3 + kx];
#pragma unroll
          for (int xx = 0; xx < 8; ++xx)
            acc[xx] = fmaf(rv[xx + kx], wv, acc[xx]);
        }
      }
    }
    __syncthreads();
  }
  float bv = bias[0];
  int base = n * 16384 + (y0 + ty) * 128 + xq * 8;
  float o[8];
#pragma unroll
  for (int xx = 0; xx < 8; ++xx) o[xx] = actf<2>(acc[xx] + bv);
  *reinterpret_cast<float4*>(&out[base]) = make_float4(o[0], o[1], o[2], o[3]);
  *reinterpret_cast<float4*>(&out[base + 4]) = make_float4(o[4], o[5], o[6], o[7]);
}

// ---------------------------------------------------------------------------
extern "C" void kernel_launch(void* const* d_in, const int* in_sizes, int n_in,
                              void* d_out, int out_size, void* d_ws, size_t ws_size,
                              hipStream_t stream) {
  (void)in_sizes; (void)n_in; (void)out_size; (void)ws_size;
  const float* x_in     = (const float*)d_in[0];
  const float* enc_w1   = (const float*)d_in[1];
  const float* enc_b1   = (const float*)d_in[2];
  const float* enc_w2   = (const float*)d_in[3];
  const float* enc_b2   = (const float*)d_in[4];
  const float* enc_w3   = (const float*)d_in[5];
  const float* enc_b3   = (const float*)d_in[6];
  const float* res_e_w1 = (const float*)d_in[7];
  const float* res_e_w2 = (const float*)d_in[8];
  const float* enc_w4   = (const float*)d_in[9];
  const float* enc_b4   = (const float*)d_in[10];
  const float* codebook = (const float*)d_in[11];
  const float* dec_w1   = (const float*)d_in[12];
  const float* dec_b1   = (const float*)d_in[13];
  const float* res_d_w1 = (const float*)d_in[14];
  const float* res_d_w2 = (const float*)d_in[15];
  const float* dec_w2   = (const float*)d_in[16];
  const float* dec_b2   = (const float*)d_in[17];
  const float* dec_w3   = (const float*)d_in[18];
  const float* dec_b3   = (const float*)d_in[19];
  float* out = (float*)d_out;

  char* ws = (char*)d_ws;
  float*  B0    = (float*)(ws);                         // 33.55 MB each
  float*  B1    = (float*)(ws + 33554432);
  float*  B2    = (float*)(ws + 67108864);
  float*  B3    = (float*)(ws + 100663296);
  float*  B4    = (float*)(ws + 134217728);             // enc1 out: 67.1 MB
  double* PART  = (double*)(ws + 201326592);
  float*  CNORM = (float*)(ws + 201326592 + 16384);
  unsigned short* CBH = (unsigned short*)(ws + 100663296);  // B3, pre-VQ only
  unsigned short* CBL = CBH + 32768;
  unsigned short* WH0 = (unsigned short*)(ws + 201359360);
  unsigned short* WL0 = WH0 + 36864;
  unsigned short* WH1 = (unsigned short*)(ws + 201359360 + 147456);
  unsigned short* WL1 = WH1 + 36864;
  unsigned short* WH2 = (unsigned short*)(ws + 201359360 + 294912);
  unsigned short* WL2 = WH2 + 36864;
  unsigned short* WH3 = (unsigned short*)(ws + 201359360 + 442368);
  unsigned short* WL3 = WH3 + 36864;
  unsigned short* WH4 = (unsigned short*)(ws + 201359360 + 589824);   // dec2
  unsigned short* WL4 = WH4 + 18432;
  unsigned short* WH5 = (unsigned short*)(ws + 201359360 + 663552);   // enc2
  unsigned short* WL5 = WH5 + 32768;
  unsigned short* WH6 = (unsigned short*)(ws + 202153984);            // res_e_w2
  unsigned short* WL6 = WH6 + 4096;
  unsigned short* WH7 = (unsigned short*)(ws + 202153984 + 16384);    // enc_w4
  unsigned short* WL7 = WH7 + 4096;
  unsigned short* WH8 = (unsigned short*)(ws + 202153984 + 32768);    // res_d_w2
  unsigned short* WL8 = WH8 + 4096;

  k_wprep<<<144, 256, 0, stream>>>(enc_w3,   WH0, WL0);
  k_wprep<<<144, 256, 0, stream>>>(res_e_w1, WH1, WL1);
  k_wprep<<<144, 256, 0, stream>>>(dec_w1,   WH2, WL2);
  k_wprep<<<144, 256, 0, stream>>>(res_d_w1, WH3, WL3);
  k_wprep2<<<72, 256, 0, stream>>>(dec_w2,   WH4, WL4);
  k_wprep_e2<<<128, 256, 0, stream>>>(enc_w2, WH5, WL5);
  k_wprep_1x1<<<16, 256, 0, stream>>>(res_e_w2, WH6, WL6);
  k_wprep_1x1<<<16, 256, 0, stream>>>(enc_w4,   WH7, WL7);
  k_wprep_1x1<<<16, 256, 0, stream>>>(res_d_w2, WH8, WL8);
  k_cbprep_m<<<128, 256, 0, stream>>>(codebook, CBH, CBL);
  k_cbnorm<<<2, 256, 0, stream>>>(codebook, CNORM);

  k_enc1m<<<1024, 256, 0, stream>>>(x_in, enc_w1, enc_b1, B4);
  k_enc2m<<<1024, 256, 0, stream>>>(B4, WH5, WL5, enc_b2, B0);
  k_conv3m<1, true ><<<512, 256, 0, stream>>>(B0, WH0, WL0, enc_b3, B1);
  k_conv3m<2, false><<<512, 256, 0, stream>>>(B1, WH1, WL1, nullptr, B2);
  k_1x1m<1, false, true ><<<2048, 256, 0, stream>>>(B2, WH6, WL6, nullptr, B1, B0);
  k_1x1m<1, true,  false><<<2048, 256, 0, stream>>>(B0, WH7, WL7, enc_b4, nullptr, B1);
  k_vq2m<<<2048, 256, 0, stream>>>(B1, CBH, CBL, codebook, CNORM, B2, PART);
  k_conv3m<1, true ><<<512, 256, 0, stream>>>(B2, WH2, WL2, dec_b1, B0);
  k_conv3m<2, false><<<512, 256, 0, stream>>>(B0, WH3, WL3, nullptr, B3);
  k_1x1m<1, false, true ><<<2048, 256, 0, stream>>>(B3, WH8, WL8, nullptr, B0, B1);
  k_dec2m<<<2048, 256, 0, stream>>>(B1, WH4, WL4, dec_b2, B4);
  k_dec3<<<1024, 256, 0, stream>>>(B4, dec_w3, dec_b3, out);
  k_loss<<<1, 256, 0, stream>>>(PART, out);
}